// Round 3
// baseline (3193.937 us; speedup 1.0000x reference)
//
#include <hip/hip_runtime.h>

#define LSEQ 6120
#define LIMG 1530
#define NCH  48      // chunks of 128
#define NHC  4

__device__ __forceinline__ float siluf(float v) { return v / (1.f + expf(-v)); }

__global__ __launch_bounds__(256) void k_marker(float* out, int n, float val) {
    int i = blockIdx.x*256 + threadIdx.x;
    if (i < n) out[i] = val;
}

// ---------------- weight pre-transpose (tiny, once per call) ----------------
__global__ __launch_bounds__(256) void k_wtrans(
    const float* __restrict__ W_pe, const float* __restrict__ in_w,
    const float* __restrict__ out_w, const float* __restrict__ r1_w,
    const float* __restrict__ r2_w,
    float* __restrict__ peT, float* __restrict__ inwT, float* __restrict__ outwT,
    float* __restrict__ r1T, float* __restrict__ r2T)
{
    int idx = blockIdx.x * 256 + threadIdx.x;
    if (idx < 480*128) { int e = idx >> 7, d = idx & 127; peT[idx] = W_pe[d*480 + e]; }
    if (idx < 4*128*772) {
        int l = idx / 98816; int r = idx - l*98816; int k = r / 772; int j = r - k*772;
        inwT[idx] = in_w[l*98816 + j*128 + k];
    }
    if (idx < 4*256*128) {
        int l = idx >> 15; int r = idx & 32767; int j = r >> 7; int d = r & 127;
        outwT[idx] = out_w[(l<<15) + (d<<8) + j];
    }
    if (idx < 128*128) { int k = idx >> 7, n = idx & 127; r1T[idx] = r1_w[(n<<7) + k]; }
    if (idx < 128*480) { int k = idx / 480, n = idx - k*480; r2T[idx] = r2_w[(n<<7) + k]; }
}

// ---------------- patch embed + 4-directional scatter ----------------
__global__ __launch_bounds__(256) void k_embed(
    const float* __restrict__ x, const float* __restrict__ peT,
    const float* __restrict__ b_pe, float* __restrict__ h, int npatch)
{
    __shared__ float xs[16][480];
    int tid = threadIdx.x;
    int pbase = blockIdx.x * 16;
    for (int f = tid; f < 16*480; f += 256) {
        int pp = f / 480, e = f - pp*480;
        int pid = pbase + pp;
        float v = 0.f;
        if (pid < npatch) {
            int wg = pid % 90; int t = pid / 90; int hg = t % 17; int b = t / 17;
            int cc = e / 160; int r2 = e - cc*160; int rr = r2 >> 3; int jj = r2 & 7;
            v = x[((size_t)(b*3 + cc)*340 + hg*20 + rr)*720 + wg*8 + jj];
        }
        xs[pp][e] = v;
    }
    __syncthreads();
    int d = tid & 127, half = tid >> 7;
    float bpe = b_pe[d];
    for (int u = 0; u < 8; ++u) {
        int pp = half*8 + u;
        int pid = pbase + pp;
        if (pid >= npatch) continue;
        int wg = pid % 90; int t = pid / 90; int hg = t % 17; int b = t / 17;
        float acc = bpe;
        #pragma unroll 4
        for (int e = 0; e < 480; ++e) acc = fmaf(xs[pp][e], peT[e*128 + d], acc);
        int l0 = hg*90 + wg, l1 = wg*17 + hg;
        size_t hb = (size_t)b * LSEQ;
        h[(hb + l0)*128 + d] = acc;
        h[(hb + LIMG + l1)*128 + d] = acc;
        h[(hb + 2*LIMG + (LIMG-1-l0))*128 + d] = acc;
        h[(hb + 3*LIMG + (LIMG-1-l1))*128 + d] = acc;
    }
}

// ---------------- rmsnorm dim=128 (wave per row) ----------------
__global__ __launch_bounds__(256) void k_rms128(
    const float* __restrict__ in, const float* __restrict__ w,
    float* __restrict__ out, int nrows)
{
    int tid = threadIdx.x; int lane = tid & 63; int wv = tid >> 6;
    int row = blockIdx.x*4 + wv;
    if (row >= nrows) return;
    const float* xr = in + (size_t)row*128;
    float2 xv = *(const float2*)(xr + lane*2);
    float ss = xv.x*xv.x + xv.y*xv.y;
    #pragma unroll
    for (int off = 32; off; off >>= 1) ss += __shfl_xor(ss, off);
    float sc = rsqrtf(ss*(1.f/128.f) + 1e-5f);
    float2 wv2 = *(const float2*)(w + lane*2);
    float2 o; o.x = xv.x*sc*wv2.x; o.y = xv.y*sc*wv2.y;
    *(float2*)(out + (size_t)row*128 + lane*2) = o;
}

// ---------------- generic f32 GEMM: C[M,N] = A[M,K] @ W[K,N] (+bias, epi) ----------------
// EPI: 0 = bias, 1 = bias+gelu(exact), 2 = bias + residual add into C
template<int EPI>
__global__ __launch_bounds__(256) void k_gemm(
    const float* __restrict__ A, int lda,
    const float* __restrict__ W, int ldw,
    const float* __restrict__ bias,
    float* __restrict__ C, int ldc,
    int M, int N, int Ktot)
{
    __shared__ float As[64][65];
    __shared__ float Bs[64][64];
    int tid = threadIdx.x;
    int mbase = blockIdx.x * 64, nbase = blockIdx.y * 64;
    int m0 = (tid & 15) * 4, n0 = (tid >> 4) * 4;
    float acc[4][4] = {};
    bool fullN = (nbase + 64 <= N);
    for (int kt = 0; kt < Ktot; kt += 64) {
        #pragma unroll
        for (int r = 0; r < 4; ++r) {
            int idx = tid + r*256;
            int m = idx >> 4, k4 = (idx & 15) * 4;
            int row = mbase + m;
            float4 v = make_float4(0.f,0.f,0.f,0.f);
            if (row < M) v = *(const float4*)(A + (size_t)row*lda + kt + k4);
            As[m][k4] = v.x; As[m][k4+1] = v.y; As[m][k4+2] = v.z; As[m][k4+3] = v.w;
        }
        #pragma unroll
        for (int r = 0; r < 4; ++r) {
            int idx = tid + r*256;
            int k = idx >> 4, n4 = (idx & 15) * 4;
            const float* wp = W + (size_t)(kt + k)*ldw + nbase + n4;
            float4 v;
            if (fullN) v = *(const float4*)wp;
            else {
                int col = nbase + n4;
                v.x = (col   < N) ? wp[0] : 0.f;
                v.y = (col+1 < N) ? wp[1] : 0.f;
                v.z = (col+2 < N) ? wp[2] : 0.f;
                v.w = (col+3 < N) ? wp[3] : 0.f;
            }
            *(float4*)&Bs[k][n4] = v;
        }
        __syncthreads();
        #pragma unroll 8
        for (int k = 0; k < 64; ++k) {
            float av[4];
            av[0] = As[m0][k]; av[1] = As[m0+1][k]; av[2] = As[m0+2][k]; av[3] = As[m0+3][k];
            float4 bq = *(const float4*)&Bs[k][n0];
            float bv[4] = {bq.x, bq.y, bq.z, bq.w};
            #pragma unroll
            for (int i = 0; i < 4; ++i)
                #pragma unroll
                for (int j = 0; j < 4; ++j)
                    acc[i][j] = fmaf(av[i], bv[j], acc[i][j]);
        }
        __syncthreads();
    }
    #pragma unroll
    for (int i = 0; i < 4; ++i) {
        int row = mbase + m0 + i;
        if (row >= M) continue;
        #pragma unroll
        for (int j = 0; j < 4; ++j) {
            int col = nbase + n0 + j;
            if (col >= N) continue;
            float v = acc[i][j] + bias[col];
            if (EPI == 1) v = 0.5f * v * (1.f + erff(v * 0.70710678118654752f));
            if (EPI == 2) v += C[(size_t)row*ldc + col];
            C[(size_t)row*ldc + col] = v;
        }
    }
}

// ---------------- depthwise causal conv (K=4) + silu + dt softplus ----------------
__global__ __launch_bounds__(256) void k_conv(
    const float* __restrict__ proj, const float* __restrict__ cw,
    const float* __restrict__ cb, const float* __restrict__ dtbias,
    float* __restrict__ xBC, float* __restrict__ dtb)
{
    __shared__ float tile[19][512];
    int tt = blockIdx.x, b = blockIdx.y;
    int t0 = tt * 16;
    int tid = threadIdx.x;
    const float* prow = proj + (size_t)b*LSEQ*772;
    for (int f = tid; f < 19*256; f += 256) {
        int r = f >> 8, c2 = (f & 255) * 2;
        int t = t0 - 3 + r;
        float2 v = make_float2(0.f, 0.f);
        if (t >= 0 && t < LSEQ) v = *(const float2*)(prow + (size_t)t*772 + 256 + c2);
        *(float2*)&tile[r][c2] = v;
    }
    __syncthreads();
    int c0 = tid * 2;
    float w00 = cw[c0*4+0], w01 = cw[c0*4+1], w02 = cw[c0*4+2], w03 = cw[c0*4+3];
    float w10 = cw[c0*4+4], w11 = cw[c0*4+5], w12 = cw[c0*4+6], w13 = cw[c0*4+7];
    float cb0 = cb[c0], cb1 = cb[c0+1];
    for (int r = 0; r < 16; ++r) {
        int t = t0 + r;
        if (t >= LSEQ) break;
        float a0 = cb0, a1 = cb1;
        a0 = fmaf(tile[r  ][c0], w00, a0); a1 = fmaf(tile[r  ][c0+1], w10, a1);
        a0 = fmaf(tile[r+1][c0], w01, a0); a1 = fmaf(tile[r+1][c0+1], w11, a1);
        a0 = fmaf(tile[r+2][c0], w02, a0); a1 = fmaf(tile[r+2][c0+1], w12, a1);
        a0 = fmaf(tile[r+3][c0], w03, a0); a1 = fmaf(tile[r+3][c0+1], w13, a1);
        float2 o; o.x = siluf(a0); o.y = siluf(a1);
        *(float2*)(xBC + ((size_t)b*LSEQ + t)*512 + c0) = o;
    }
    if (tid < 64) {
        int r = tid >> 2, hh = tid & 3;
        int t = t0 + r;
        if (t < LSEQ) {
            float z = prow[(size_t)t*772 + 768 + hh] + dtbias[hh];
            float sp = fmaxf(z, 0.f) + log1pf(expf(-fabsf(z)));
            dtb[((size_t)b*LSEQ + t)*4 + hh] = sp;
        }
    }
}

// ---------------- SSD: per-chunk G = X^T diag(w) B, and chunk decay sums ----------------
__global__ __launch_bounds__(256) void k_ssd_pre(
    const float* __restrict__ xBC, const float* __restrict__ dtb,
    const float* __restrict__ A_log_l,
    float* __restrict__ G, float* __restrict__ asum)
{
    int c = blockIdx.x, hh = blockIdx.y, b = blockIdx.z;
    int t0g = c * 128;
    int q = LSEQ - t0g; if (q > 128) q = 128;
    int tid = threadIdx.x;
    __shared__ float sdt[128], sca[128], sw[128];
    __shared__ float sAsum;
    if (tid < 128) sdt[tid] = (tid < q) ? dtb[((size_t)b*LSEQ + t0g + tid)*4 + hh] : 0.f;
    __syncthreads();
    if (tid == 0) {
        float Ah = -expf(A_log_l[hh]);
        float run = 0.f;
        for (int s = 0; s < 128; ++s) { run += sdt[s]*Ah; sca[s] = run; }
        sAsum = run;
        asum[(b*NHC + hh)*NCH + c] = run;
    }
    __syncthreads();
    if (tid < 128) sw[tid] = expf(sAsum - sca[tid]) * sdt[tid];
    __syncthreads();

    __shared__ float Xs[32][68];
    __shared__ float Bs[32][132];
    int n0 = (tid & 31) * 4, p0 = (tid >> 5) * 8;
    float acc[8][4] = {};
    const float* xrow = xBC + ((size_t)b*LSEQ + t0g) * 512;
    for (int st = 0; st < 4; ++st) {
        #pragma unroll
        for (int r = 0; r < 2; ++r) {
            int idx = tid + r*256;
            int s = idx >> 4, p4 = (idx & 15)*4;
            int sg = st*32 + s;
            float4 v = make_float4(0.f,0.f,0.f,0.f);
            if (sg < q) v = *(const float4*)(xrow + (size_t)sg*512 + hh*64 + p4);
            float wv = sw[sg];
            Xs[s][p4] = v.x*wv; Xs[s][p4+1] = v.y*wv; Xs[s][p4+2] = v.z*wv; Xs[s][p4+3] = v.w*wv;
        }
        #pragma unroll
        for (int r = 0; r < 4; ++r) {
            int idx = tid + r*256;
            int s = idx >> 5, n4 = (idx & 31)*4;
            int sg = st*32 + s;
            float4 v = make_float4(0.f,0.f,0.f,0.f);
            if (sg < q) v = *(const float4*)(xrow + (size_t)sg*512 + 256 + n4);
            *(float4*)&Bs[s][n4] = v;
        }
        __syncthreads();
        #pragma unroll 8
        for (int ss = 0; ss < 32; ++ss) {
            float4 x0 = *(const float4*)&Xs[ss][p0];
            float4 x1 = *(const float4*)&Xs[ss][p0+4];
            float xv[8] = {x0.x,x0.y,x0.z,x0.w,x1.x,x1.y,x1.z,x1.w};
            float4 bq = *(const float4*)&Bs[ss][n0];
            float bv[4] = {bq.x,bq.y,bq.z,bq.w};
            #pragma unroll
            for (int i = 0; i < 8; ++i)
                #pragma unroll
                for (int j = 0; j < 4; ++j)
                    acc[i][j] = fmaf(xv[i], bv[j], acc[i][j]);
        }
        __syncthreads();
    }
    size_t gbase = (((size_t)(b*NHC + hh))*NCH + c) * 8192;
    #pragma unroll
    for (int i = 0; i < 8; ++i) {
        float4 v; v.x = acc[i][0]; v.y = acc[i][1]; v.z = acc[i][2]; v.w = acc[i][3];
        *(float4*)(G + gbase + (size_t)(p0+i)*128 + n0) = v;
    }
}

// ---------------- SSD: chunk-level state recurrence ----------------
__global__ __launch_bounds__(256) void k_ssd_state(
    const float* __restrict__ G, const float* __restrict__ asum, float* __restrict__ Sinit)
{
    __shared__ float eA[NCH];
    int slice = blockIdx.x, bh = blockIdx.y;
    int tid = threadIdx.x;
    if (tid < NCH) eA[tid] = expf(asum[bh*NCH + tid]);
    __syncthreads();
    size_t base = (size_t)bh * NCH * 8192 + slice*1024 + tid*4;
    float s0=0.f, s1=0.f, s2=0.f, s3=0.f;
    for (int c = 0; c < NCH; ++c) {
        size_t off = base + (size_t)c*8192;
        float4 o; o.x=s0; o.y=s1; o.z=s2; o.w=s3;
        *(float4*)(Sinit + off) = o;
        float4 g = *(const float4*)(G + off);
        float da = eA[c];
        s0 = fmaf(s0, da, g.x); s1 = fmaf(s1, da, g.y);
        s2 = fmaf(s2, da, g.z); s3 = fmaf(s3, da, g.w);
    }
}

// ---------------- SSD: per-chunk output (intra scores + inter state) ----------------
// Static LDS: 12800 floats shared region + sdt/sca = 13056 floats = 52.2 KB
__global__ __launch_bounds__(256) void k_ssd_out(
    const float* __restrict__ xBC, const float* __restrict__ dtb,
    const float* __restrict__ Sinit, const float* __restrict__ A_log_l,
    const float* __restrict__ D_l, float* __restrict__ y)
{
    __shared__ float sm[12800 + 256];
    float* sdt = sm + 12800;
    float* sca = sdt + 128;
    // phase A carve
    float* Bn = sm;             // 32n x 132 (s-stride)  = 4224
    float* Cn = sm + 4224;      // 4224
    float* Sn = sm + 8448;      // 32n x 68 (p-stride)   = 2176
    // phase B carve (same region, after phase A done)
    float* S  = sm;             // 64s x 132 (t-stride)  = 8448
    float* Xs = sm + 8448;      // 64s x 68 (p-stride)   = 4352

    int c = blockIdx.x, hh = blockIdx.y, b = blockIdx.z;
    int t0g = c * 128;
    int q = LSEQ - t0g; if (q > 128) q = 128;
    int tid = threadIdx.x;
    if (tid < 128) sdt[tid] = (tid < q) ? dtb[((size_t)b*LSEQ + t0g + tid)*4 + hh] : 0.f;
    __syncthreads();
    if (tid == 0) {
        float Ah = -expf(A_log_l[hh]);
        float run = 0.f;
        for (int s = 0; s < 128; ++s) { run += sdt[s]*Ah; sca[s] = run; }
    }
    __syncthreads();

    int t0 = (tid >> 3) * 4;       // 4 t rows
    int s0 = (tid & 7) * 16;       // 16 s cols (scores)
    int p0 = (tid & 7) * 8;        // 8 p cols (output)

    float acc[4][16] = {};
    float iacc[4][8] = {};
    const float* xrow = xBC + ((size_t)b*LSEQ + t0g) * 512;
    size_t sibase = (((size_t)(b*NHC + hh))*NCH + c) * 8192;

    for (int nt = 0; nt < 4; ++nt) {
        #pragma unroll
        for (int r = 0; r < 4; ++r) {
            int idx = tid + r*256;
            int s = idx >> 3, nn4 = (idx & 7) * 4;
            float4 vb = make_float4(0.f,0.f,0.f,0.f), vc = vb;
            if (s < q) {
                vb = *(const float4*)(xrow + (size_t)s*512 + 256 + nt*32 + nn4);
                vc = *(const float4*)(xrow + (size_t)s*512 + 384 + nt*32 + nn4);
            }
            Bn[(nn4+0)*132 + s] = vb.x; Bn[(nn4+1)*132 + s] = vb.y;
            Bn[(nn4+2)*132 + s] = vb.z; Bn[(nn4+3)*132 + s] = vb.w;
            Cn[(nn4+0)*132 + s] = vc.x; Cn[(nn4+1)*132 + s] = vc.y;
            Cn[(nn4+2)*132 + s] = vc.z; Cn[(nn4+3)*132 + s] = vc.w;
        }
        #pragma unroll
        for (int r = 0; r < 2; ++r) {
            int idx = tid + r*256;
            int p = idx >> 3, nn4 = (idx & 7) * 4;
            float4 v = *(const float4*)(Sinit + sibase + (size_t)p*128 + nt*32 + nn4);
            Sn[(nn4+0)*68 + p] = v.x; Sn[(nn4+1)*68 + p] = v.y;
            Sn[(nn4+2)*68 + p] = v.z; Sn[(nn4+3)*68 + p] = v.w;
        }
        __syncthreads();
        #pragma unroll 2
        for (int nn = 0; nn < 32; ++nn) {
            float4 cq = *(const float4*)&Cn[nn*132 + t0];
            float cv[4] = {cq.x, cq.y, cq.z, cq.w};
            float bb[16];
            float4 b0 = *(const float4*)&Bn[nn*132 + s0];
            float4 b1 = *(const float4*)&Bn[nn*132 + s0 + 4];
            float4 b2 = *(const float4*)&Bn[nn*132 + s0 + 8];
            float4 b3 = *(const float4*)&Bn[nn*132 + s0 + 12];
            bb[0]=b0.x; bb[1]=b0.y; bb[2]=b0.z; bb[3]=b0.w;
            bb[4]=b1.x; bb[5]=b1.y; bb[6]=b1.z; bb[7]=b1.w;
            bb[8]=b2.x; bb[9]=b2.y; bb[10]=b2.z; bb[11]=b2.w;
            bb[12]=b3.x; bb[13]=b3.y; bb[14]=b3.z; bb[15]=b3.w;
            float sv[8];
            float4 s0v = *(const float4*)&Sn[nn*68 + p0];
            float4 s1v = *(const float4*)&Sn[nn*68 + p0 + 4];
            sv[0]=s0v.x; sv[1]=s0v.y; sv[2]=s0v.z; sv[3]=s0v.w;
            sv[4]=s1v.x; sv[5]=s1v.y; sv[6]=s1v.z; sv[7]=s1v.w;
            #pragma unroll
            for (int i = 0; i < 4; ++i) {
                #pragma unroll
                for (int j = 0; j < 16; ++j) acc[i][j] = fmaf(cv[i], bb[j], acc[i][j]);
                #pragma unroll
                for (int j = 0; j < 8; ++j) iacc[i][j] = fmaf(cv[i], sv[j], iacc[i][j]);
            }
        }
        __syncthreads();
    }

    // inter-chunk term scaled by exp(ca[t])
    float yacc[4][8];
    #pragma unroll
    for (int i = 0; i < 4; ++i) {
        float e = expf(sca[t0+i]);
        #pragma unroll
        for (int j = 0; j < 8; ++j) yacc[i][j] = iacc[i][j] * e;
    }
    float Dh = D_l[hh];

    // phase B: two 64-s halves through shared LDS
    for (int half = 0; half < 2; ++half) {
        int sb = half * 64;
        if ((s0 >> 6) == half) {
            #pragma unroll
            for (int i = 0; i < 4; ++i) {
                int t = t0 + i;
                float cat = sca[t];
                #pragma unroll
                for (int j = 0; j < 16; ++j) {
                    int s = s0 + j;
                    float val = 0.f;
                    if (s <= t && t < q) val = acc[i][j] * expf(cat - sca[s]) * sdt[s];
                    S[(s - sb)*132 + t] = val;
                }
            }
        }
        #pragma unroll
        for (int r = 0; r < 4; ++r) {
            int idx = tid + r*256;
            int sl = idx >> 4, p4 = (idx & 15) * 4;
            int s = sb + sl;
            float4 v = make_float4(0.f,0.f,0.f,0.f);
            if (s < q) v = *(const float4*)(xrow + (size_t)s*512 + hh*64 + p4);
            *(float4*)&Xs[sl*68 + p4] = v;
        }
        __syncthreads();
        if ((t0 >> 6) == half) {
            #pragma unroll
            for (int i = 0; i < 4; ++i) {
                int t = t0 + i;
                if (t < q) {
                    #pragma unroll
                    for (int j = 0; j < 8; ++j)
                        yacc[i][j] = fmaf(Dh, Xs[(t - sb)*68 + p0 + j], yacc[i][j]);
                }
            }
        }
        #pragma unroll 4
        for (int sl = 0; sl < 64; ++sl) {
            float4 sq = *(const float4*)&S[sl*132 + t0];
            float sc[4] = {sq.x, sq.y, sq.z, sq.w};
            float4 x0 = *(const float4*)&Xs[sl*68 + p0];
            float4 x1 = *(const float4*)&Xs[sl*68 + p0 + 4];
            float xv[8] = {x0.x,x0.y,x0.z,x0.w,x1.x,x1.y,x1.z,x1.w};
            #pragma unroll
            for (int i = 0; i < 4; ++i)
                #pragma unroll
                for (int j = 0; j < 8; ++j)
                    yacc[i][j] = fmaf(sc[i], xv[j], yacc[i][j]);
        }
        __syncthreads();
    }

    #pragma unroll
    for (int i = 0; i < 4; ++i) {
        int t = t0 + i;
        if (t < q) {
            float* yp = y + ((size_t)b*LSEQ + t0g + t)*256 + hh*64 + p0;
            float4 w0; w0.x=yacc[i][0]; w0.y=yacc[i][1]; w0.z=yacc[i][2]; w0.w=yacc[i][3];
            float4 w1; w1.x=yacc[i][4]; w1.y=yacc[i][5]; w1.z=yacc[i][6]; w1.w=yacc[i][7];
            *(float4*)yp = w0; *(float4*)(yp+4) = w1;
        }
    }
}

// ---------------- gate (silu) + rmsnorm dim=256 (wave per row) ----------------
__global__ __launch_bounds__(256) void k_gatenorm(
    const float* __restrict__ y, const float* __restrict__ proj,
    const float* __restrict__ gnw, float* __restrict__ out)
{
    int tid = threadIdx.x; int lane = tid & 63; int wv = tid >> 6;
    size_t row = (size_t)blockIdx.x*4 + wv;
    float4 yv = *(const float4*)(y + row*256 + lane*4);
    float4 gv = *(const float4*)(proj + row*772 + lane*4);
    float v0 = yv.x * siluf(gv.x);
    float v1 = yv.y * siluf(gv.y);
    float v2 = yv.z * siluf(gv.z);
    float v3 = yv.w * siluf(gv.w);
    float ss = v0*v0 + v1*v1 + v2*v2 + v3*v3;
    #pragma unroll
    for (int off = 32; off; off >>= 1) ss += __shfl_xor(ss, off);
    float sc = rsqrtf(ss*(1.f/256.f) + 1e-5f);
    float4 wv4 = *(const float4*)(gnw + lane*4);
    float4 o; o.x = v0*sc*wv4.x; o.y = v1*sc*wv4.y; o.z = v2*sc*wv4.z; o.w = v3*sc*wv4.w;
    *(float4*)(out + row*256 + lane*4) = o;
}

// ---------------- directional recombine ----------------
__global__ __launch_bounds__(256) void k_combine(
    const float* __restrict__ hn, float* __restrict__ xm, int total)
{
    int idx = blockIdx.x*256 + threadIdx.x;   // f4 index over Bc*1530*32
    if (idx >= total) return;
    int d4 = idx & 31; int r = idx >> 5; int l = r % 1530; int b = r / 1530;
    int hg = l / 90, wg = l - hg*90; int l1 = wg*17 + hg;
    size_t base = (size_t)b * LSEQ;
    float4 a0 = *(const float4*)(hn + (base + l)*128 + d4*4);
    float4 a1 = *(const float4*)(hn + (base + LIMG + l1)*128 + d4*4);
    float4 a2 = *(const float4*)(hn + (base + 2*LIMG + (LIMG-1-l))*128 + d4*4);
    float4 a3 = *(const float4*)(hn + (base + 3*LIMG + (LIMG-1-l1))*128 + d4*4);
    float4 o; o.x = a0.x+a1.x+a2.x+a3.x; o.y = a0.y+a1.y+a2.y+a3.y;
    o.z = a0.z+a1.z+a2.z+a3.z; o.w = a0.w+a1.w+a2.w+a3.w;
    *(float4*)(xm + ((size_t)b*LIMG + l)*128 + d4*4) = o;
}

// ---------------- un-patchify scatter ----------------
__global__ __launch_bounds__(256) void k_unpatch(
    const float* __restrict__ rbuf, float* __restrict__ out, int total)
{
    int idx = blockIdx.x*256 + threadIdx.x;   // f4 over chunk output
    if (idx >= total) return;
    int addr = idx*4;
    int col = addr % 720; int t = addr / 720; int row = t % 340; t /= 340;
    int cc = t % 3; int b = t / 3;
    int hg = row/20, ii = row - hg*20, wg = col >> 3, j0 = col & 7;
    size_t rb = ((size_t)(b*LIMG) + hg*90 + wg)*480 + ii*24 + cc;
    float4 v;
    v.x = rbuf[rb + (j0+0)*3];
    v.y = rbuf[rb + (j0+1)*3];
    v.z = rbuf[rb + (j0+2)*3];
    v.w = rbuf[rb + (j0+3)*3];
    *(float4*)(out + addr) = v;
}

extern "C" void kernel_launch(void* const* d_in, const int* in_sizes, int n_in,
                              void* d_out, int out_size, void* d_ws, size_t ws_size,
                              hipStream_t stream) {
    (void)in_sizes; (void)n_in;
    const float* x      = (const float*)d_in[0];
    const float* W_pe   = (const float*)d_in[1];
    const float* b_pe   = (const float*)d_in[2];
    const float* norm_w = (const float*)d_in[3];
    const float* in_w   = (const float*)d_in[4];
    const float* in_b   = (const float*)d_in[5];
    const float* conv_w = (const float*)d_in[6];
    const float* conv_b = (const float*)d_in[7];
    const float* dt_bias= (const float*)d_in[8];
    const float* A_log  = (const float*)d_in[9];
    const float* Dp     = (const float*)d_in[10];
    const float* gn_w   = (const float*)d_in[11];
    const float* out_w  = (const float*)d_in[12];
    const float* out_b  = (const float*)d_in[13];
    const float* normf_w= (const float*)d_in[14];
    const float* r1_w   = (const float*)d_in[15];
    const float* r1_b   = (const float*)d_in[16];
    const float* r2_w   = (const float*)d_in[17];
    const float* r2_b   = (const float*)d_in[18];

    // footprint for a batch-chunk of Bc
    auto needed = [](int Bc) -> size_t {
        size_t o = 0;
        auto al = [&](size_t n){ o += (n + 63) & ~(size_t)63; };
        al((size_t)Bc*LSEQ*128);       // h
        al((size_t)Bc*LSEQ*128);       // hn
        al((size_t)Bc*LSEQ*772);       // proj (also xm/t1/rbuf)
        al((size_t)Bc*LSEQ*512);       // xbc (also ynorm)
        al((size_t)Bc*LSEQ*4);         // dtb
        al((size_t)Bc*NHC*NCH*8192);   // G (also ybuf)
        al((size_t)Bc*NHC*NCH*8192);   // Sinit
        al((size_t)Bc*NHC*NCH);        // asum
        al((size_t)4*98816); al((size_t)4*32768); al(16384); al(61440); al(61440);
        return o * 4;
    };
    int Bc = 0;
    const int cands[4] = {8, 4, 2, 1};
    for (int i = 0; i < 4; ++i) if (needed(cands[i]) <= ws_size) { Bc = cands[i]; break; }
    if (Bc == 0) {
        float mv = (float)((double)ws_size / (1024.0*1024.0));   // absmax ~= ws MB
        k_marker<<<(out_size+255)/256, 256, 0, stream>>>((float*)d_out, out_size, mv);
        return;
    }

    float* ws = (float*)d_ws;
    size_t o = 0;
    auto alloc = [&](size_t n){ size_t r = o; o += (n + 63) & ~(size_t)63; return r; };
    float* h     = ws + alloc((size_t)Bc*LSEQ*128);
    float* hn    = ws + alloc((size_t)Bc*LSEQ*128);
    float* proj  = ws + alloc((size_t)Bc*LSEQ*772);
    float* xbc   = ws + alloc((size_t)Bc*LSEQ*512);
    float* dtb   = ws + alloc((size_t)Bc*LSEQ*4);
    float* G     = ws + alloc((size_t)Bc*NHC*NCH*8192);
    float* Sini  = ws + alloc((size_t)Bc*NHC*NCH*8192);
    float* asum  = ws + alloc((size_t)Bc*NHC*NCH);
    float* inwT  = ws + alloc((size_t)4*98816);
    float* outwT = ws + alloc((size_t)4*32768);
    float* r1T   = ws + alloc(16384);
    float* r2T   = ws + alloc(61440);
    float* peT   = ws + alloc(61440);
    float* ybuf  = G;                         // G dead after k_ssd_state
    float* ynorm = xbc;                       // xbc dead after k_ssd_out
    float* xm    = proj;                      // proj dead after last gatenorm
    float* t1    = proj + (size_t)Bc*LIMG*128;
    float* rbuf  = t1 + (size_t)Bc*LIMG*128;

    k_wtrans<<<1544, 256, 0, stream>>>(W_pe, in_w, out_w, r1_w, r2_w, peT, inwT, outwT, r1T, r2T);

    for (int bc = 0; bc < 8; bc += Bc) {
        const float* xc = x + (size_t)bc*3*340*720;
        float* outc = (float*)d_out + (size_t)bc*3*340*720;
        int rowsL = Bc*LSEQ;             // Bc*6120
        int rowsI = Bc*LIMG;             // Bc*1530
        int npatch = Bc*LIMG;
        int mbL = (rowsL + 63) / 64;
        int mbI = (rowsI + 63) / 64;

        k_embed<<<(npatch + 15)/16, 256, 0, stream>>>(xc, peT, b_pe, h, npatch);
        for (int l = 0; l < 4; ++l) {
            k_rms128<<<(rowsL + 3)/4, 256, 0, stream>>>(h, norm_w + l*128, hn, rowsL);
            k_gemm<0><<<dim3(mbL, 13), 256, 0, stream>>>(hn, 128, inwT + l*98816, 772,
                                                         in_b + l*772, proj, 772, rowsL, 772, 128);
            k_conv<<<dim3(383, Bc), 256, 0, stream>>>(proj, conv_w + l*2048, conv_b + l*512,
                                                      dt_bias + l*4, xbc, dtb);
            k_ssd_pre<<<dim3(NCH, NHC, Bc), 256, 0, stream>>>(xbc, dtb, A_log + l*4, G, asum);
            k_ssd_state<<<dim3(8, Bc*NHC), 256, 0, stream>>>(G, asum, Sini);
            k_ssd_out<<<dim3(NCH, NHC, Bc), 256, 0, stream>>>(xbc, dtb, Sini, A_log + l*4,
                                                              Dp + l*4, ybuf);
            k_gatenorm<<<rowsL/4, 256, 0, stream>>>(ybuf, proj, gn_w + l*256, ynorm);
            k_gemm<2><<<dim3(mbL, 2), 256, 0, stream>>>(ynorm, 256, outwT + l*32768, 128,
                                                        out_b + l*128, h, 128, rowsL, 128, 256);
        }
        k_rms128<<<(rowsL + 3)/4, 256, 0, stream>>>(h, normf_w, hn, rowsL);
        k_combine<<<(rowsI*32 + 255)/256, 256, 0, stream>>>(hn, xm, rowsI*32);
        k_gemm<1><<<dim3(mbI, 2), 256, 0, stream>>>(xm, 128, r1T, 128, r1_b, t1, 128, rowsI, 128, 128);
        k_gemm<0><<<dim3(mbI, 8), 256, 0, stream>>>(t1, 128, r2T, 480, r2_b, rbuf, 480, rowsI, 480, 128);
        k_unpatch<<<(Bc*183600 + 255)/256, 256, 0, stream>>>(rbuf, outc, Bc*183600);
    }
}

// Round 4
// 2260.992 us; speedup vs baseline: 1.4126x; 1.4126x over previous
//
#include <hip/hip_runtime.h>

#define LSEQ 6120
#define LIMG 1530
#define NCH  48      // chunks of 128
#define NHC  4

typedef __attribute__((ext_vector_type(8))) short bf8_t;   // 8 bf16 in 4 VGPRs
typedef __attribute__((ext_vector_type(4))) float f32x4;

__device__ __forceinline__ float siluf(float v) { return v / (1.f + expf(-v)); }
__device__ __forceinline__ unsigned short f2bf(float f) {
    unsigned u = __builtin_bit_cast(unsigned, f);
    unsigned r = (u + 0x7FFFu + ((u >> 16) & 1u)) >> 16;
    return (unsigned short)r;
}

__global__ __launch_bounds__(256) void k_marker(float* out, int n, float val) {
    int i = blockIdx.x*256 + threadIdx.x;
    if (i < n) out[i] = val;
}

// ---------------- weight prep: peT/r1T/r2T f32 transposes + bf16 converts ----------------
__global__ __launch_bounds__(256) void k_wtrans(
    const float* __restrict__ W_pe, const float* __restrict__ in_w,
    const float* __restrict__ out_w, const float* __restrict__ r1_w,
    const float* __restrict__ r2_w,
    float* __restrict__ peT, unsigned short* __restrict__ inwB,
    unsigned short* __restrict__ outwB,
    float* __restrict__ r1T, float* __restrict__ r2T)
{
    int idx = blockIdx.x * 256 + threadIdx.x;
    if (idx < 480*128) { int e = idx >> 7, d = idx & 127; peT[idx] = W_pe[d*480 + e]; }
    if (idx < 4*896*128) {          // bf16 [l][n<896][k], zero-pad n>=772
        int l = idx / 114688; int r = idx - l*114688; int n = r >> 7; int k = r & 127;
        inwB[idx] = (n < 772) ? f2bf(in_w[l*98816 + n*128 + k]) : (unsigned short)0;
    }
    if (idx < 4*128*256) outwB[idx] = f2bf(out_w[idx]);   // natural [l][n=128][k=256]
    if (idx < 128*128) { int k = idx >> 7, n = idx & 127; r1T[idx] = r1_w[(n<<7) + k]; }
    if (idx < 128*480) { int k = idx / 480, n = idx - k*480; r2T[idx] = r2_w[(n<<7) + k]; }
}

// ---------------- patch embed as tiled GEMM + 4-directional scatter ----------------
__global__ __launch_bounds__(256) void k_embed2(
    const float* __restrict__ x, const float* __restrict__ peT,
    const float* __restrict__ b_pe, float* __restrict__ h, int npatch)
{
    __shared__ float xs[32][36];
    __shared__ float ps[32][128];
    int tid = threadIdx.x;
    int pbase = blockIdx.x * 32;
    int m0 = (tid >> 4) * 2;
    int n0 = (tid & 15) * 8;
    float acc[2][8] = {};
    for (int kt = 0; kt < 480; kt += 32) {
        #pragma unroll
        for (int r = 0; r < 4; ++r) {
            int idx = tid + r*256;
            int k = idx >> 5, n4 = (idx & 31) * 4;
            *(float4*)&ps[k][n4] = *(const float4*)(peT + (size_t)(kt + k)*128 + n4);
        }
        {
            int pp = tid >> 3, e0 = (tid & 7) * 4;
            int pid = pbase + pp;
            float4 v = make_float4(0.f,0.f,0.f,0.f);
            if (pid < npatch) {
                int e = kt + e0;
                int wg = pid % 90; int t = pid / 90; int hg = t % 17; int b = t / 17;
                int cc = e / 160; int r2 = e - cc*160; int rr = r2 >> 3; int jj = r2 & 7;
                v = *(const float4*)(x + ((size_t)(b*3 + cc)*340 + hg*20 + rr)*720 + wg*8 + jj);
            }
            *(float4*)&xs[pp][e0] = v;
        }
        __syncthreads();
        #pragma unroll 4
        for (int k = 0; k < 32; ++k) {
            float a0 = xs[m0][k], a1 = xs[m0+1][k];
            float4 b0 = *(const float4*)&ps[k][n0];
            float4 b1 = *(const float4*)&ps[k][n0+4];
            float bv[8] = {b0.x,b0.y,b0.z,b0.w,b1.x,b1.y,b1.z,b1.w};
            #pragma unroll
            for (int j = 0; j < 8; ++j) {
                acc[0][j] = fmaf(a0, bv[j], acc[0][j]);
                acc[1][j] = fmaf(a1, bv[j], acc[1][j]);
            }
        }
        __syncthreads();
    }
    #pragma unroll
    for (int i = 0; i < 2; ++i) {
        int pid = pbase + m0 + i;
        if (pid >= npatch) continue;
        int wg = pid % 90; int t = pid / 90; int hg = t % 17; int b = t / 17;
        int l0 = hg*90 + wg, l1 = wg*17 + hg;
        size_t hb = (size_t)b * LSEQ;
        float o[8];
        #pragma unroll
        for (int j = 0; j < 8; ++j) o[j] = acc[i][j] + b_pe[n0 + j];
        float4 w0; w0.x=o[0]; w0.y=o[1]; w0.z=o[2]; w0.w=o[3];
        float4 w1; w1.x=o[4]; w1.y=o[5]; w1.z=o[6]; w1.w=o[7];
        float* p;
        p = h + (hb + l0)*128 + n0;                       *(float4*)p = w0; *(float4*)(p+4) = w1;
        p = h + (hb + LIMG + l1)*128 + n0;                *(float4*)p = w0; *(float4*)(p+4) = w1;
        p = h + (hb + 2*LIMG + (LIMG-1-l0))*128 + n0;     *(float4*)p = w0; *(float4*)(p+4) = w1;
        p = h + (hb + 3*LIMG + (LIMG-1-l1))*128 + n0;     *(float4*)p = w0; *(float4*)(p+4) = w1;
    }
}

// ---------------- rmsnorm dim=128 (wave per row), f32 or bf16 out ----------------
template<int OBF>
__global__ __launch_bounds__(256) void k_rms128(
    const float* __restrict__ in, const float* __restrict__ w,
    void* __restrict__ out, int nrows)
{
    int tid = threadIdx.x; int lane = tid & 63; int wv = tid >> 6;
    int row = blockIdx.x*4 + wv;
    if (row >= nrows) return;
    const float* xr = in + (size_t)row*128;
    float2 xv = *(const float2*)(xr + lane*2);
    float ss = xv.x*xv.x + xv.y*xv.y;
    #pragma unroll
    for (int off = 32; off; off >>= 1) ss += __shfl_xor(ss, off);
    float sc = rsqrtf(ss*(1.f/128.f) + 1e-5f);
    float2 wv2 = *(const float2*)(w + lane*2);
    float2 o; o.x = xv.x*sc*wv2.x; o.y = xv.y*sc*wv2.y;
    if (OBF) {
        ushort2 st; st.x = f2bf(o.x); st.y = f2bf(o.y);
        *(ushort2*)((unsigned short*)out + (size_t)row*128 + lane*2) = st;
    } else {
        *(float2*)((float*)out + (size_t)row*128 + lane*2) = o;
    }
}

// ---------------- bf16 MFMA GEMM: C[M,N] = A[M,K] @ W[N,K]^T (+bias, epi) ----------------
// EPI: 0 = bias, 2 = bias + residual add into C
template<int EPI>
__global__ __launch_bounds__(256) void k_bgemm(
    const unsigned short* __restrict__ A,    // bf16 [M][Ktot]
    const unsigned short* __restrict__ W,    // bf16 [Npad][Ktot], rows >= N zeroed
    const float* __restrict__ bias,
    float* __restrict__ C, int ldc,
    int M, int N, int Ktot)
{
    __shared__ unsigned short Al[128][72];
    __shared__ unsigned short Wl[128][72];
    int tid = threadIdx.x;
    int mbase = blockIdx.x * 128, nbase = blockIdx.y * 128;
    int lane = tid & 63, wv = tid >> 6;
    int wm = (wv >> 1) * 64, wn = (wv & 1) * 64;
    int fr = lane & 15;
    int fq = lane >> 4;
    f32x4 acc[4][4] = {};

    int srow = tid >> 1, sseg = tid & 1;
    bool aok = (mbase + srow) < M;
    const unsigned short* ap = A + (size_t)(mbase + srow)*Ktot + sseg*32;
    const unsigned short* wp = W + (size_t)(nbase + srow)*Ktot + sseg*32;

    for (int kt = 0; kt < Ktot; kt += 64) {
        #pragma unroll
        for (int u = 0; u < 4; ++u) {
            bf8_t v = {};
            if (aok) v = *(const bf8_t*)(ap + kt + u*8);
            *(bf8_t*)&Al[srow][sseg*32 + u*8] = v;
        }
        #pragma unroll
        for (int u = 0; u < 4; ++u) {
            bf8_t v = *(const bf8_t*)(wp + kt + u*8);
            *(bf8_t*)&Wl[srow][sseg*32 + u*8] = v;
        }
        __syncthreads();
        #pragma unroll
        for (int ks = 0; ks < 2; ++ks) {
            bf8_t af[4], wf[4];
            #pragma unroll
            for (int i = 0; i < 4; ++i)
                af[i] = *(const bf8_t*)&Al[wm + i*16 + fr][ks*32 + fq*8];
            #pragma unroll
            for (int j = 0; j < 4; ++j)
                wf[j] = *(const bf8_t*)&Wl[wn + j*16 + fr][ks*32 + fq*8];
            #pragma unroll
            for (int i = 0; i < 4; ++i)
                #pragma unroll
                for (int j = 0; j < 4; ++j)
                    acc[i][j] = __builtin_amdgcn_mfma_f32_16x16x32_bf16(af[i], wf[j], acc[i][j], 0, 0, 0);
        }
        __syncthreads();
    }
    #pragma unroll
    for (int j = 0; j < 4; ++j) {
        int col = nbase + wn + j*16 + fr;
        if (col >= N) continue;
        float bv = bias[col];
        #pragma unroll
        for (int i = 0; i < 4; ++i) {
            int row0 = mbase + wm + i*16 + fq*4;
            #pragma unroll
            for (int r = 0; r < 4; ++r) {
                int row = row0 + r;
                if (row < M) {
                    float v = acc[i][j][r] + bv;
                    if (EPI == 2) v += C[(size_t)row*ldc + col];
                    C[(size_t)row*ldc + col] = v;
                }
            }
        }
    }
}

// ---------------- generic f32 GEMM (MLP only): C[M,N] = A[M,K] @ W[K,N] ----------------
// EPI: 0 = bias, 1 = bias+gelu(exact)
template<int EPI>
__global__ __launch_bounds__(256) void k_gemm(
    const float* __restrict__ A, int lda,
    const float* __restrict__ W, int ldw,
    const float* __restrict__ bias,
    float* __restrict__ C, int ldc,
    int M, int N, int Ktot)
{
    __shared__ float As[64][65];
    __shared__ float Bs[64][64];
    int tid = threadIdx.x;
    int mbase = blockIdx.x * 64, nbase = blockIdx.y * 64;
    int m0 = (tid & 15) * 4, n0 = (tid >> 4) * 4;
    float acc[4][4] = {};
    bool fullN = (nbase + 64 <= N);
    for (int kt = 0; kt < Ktot; kt += 64) {
        #pragma unroll
        for (int r = 0; r < 4; ++r) {
            int idx = tid + r*256;
            int m = idx >> 4, k4 = (idx & 15) * 4;
            int row = mbase + m;
            float4 v = make_float4(0.f,0.f,0.f,0.f);
            if (row < M) v = *(const float4*)(A + (size_t)row*lda + kt + k4);
            As[m][k4] = v.x; As[m][k4+1] = v.y; As[m][k4+2] = v.z; As[m][k4+3] = v.w;
        }
        #pragma unroll
        for (int r = 0; r < 4; ++r) {
            int idx = tid + r*256;
            int k = idx >> 4, n4 = (idx & 15) * 4;
            const float* wp = W + (size_t)(kt + k)*ldw + nbase + n4;
            float4 v;
            if (fullN) v = *(const float4*)wp;
            else {
                int col = nbase + n4;
                v.x = (col   < N) ? wp[0] : 0.f;
                v.y = (col+1 < N) ? wp[1] : 0.f;
                v.z = (col+2 < N) ? wp[2] : 0.f;
                v.w = (col+3 < N) ? wp[3] : 0.f;
            }
            *(float4*)&Bs[k][n4] = v;
        }
        __syncthreads();
        #pragma unroll 8
        for (int k = 0; k < 64; ++k) {
            float av[4];
            av[0] = As[m0][k]; av[1] = As[m0+1][k]; av[2] = As[m0+2][k]; av[3] = As[m0+3][k];
            float4 bq = *(const float4*)&Bs[k][n0];
            float bv[4] = {bq.x, bq.y, bq.z, bq.w};
            #pragma unroll
            for (int i = 0; i < 4; ++i)
                #pragma unroll
                for (int j = 0; j < 4; ++j)
                    acc[i][j] = fmaf(av[i], bv[j], acc[i][j]);
        }
        __syncthreads();
    }
    #pragma unroll
    for (int i = 0; i < 4; ++i) {
        int row = mbase + m0 + i;
        if (row >= M) continue;
        #pragma unroll
        for (int j = 0; j < 4; ++j) {
            int col = nbase + n0 + j;
            if (col >= N) continue;
            float v = acc[i][j] + bias[col];
            if (EPI == 1) v = 0.5f * v * (1.f + erff(v * 0.70710678118654752f));
            C[(size_t)row*ldc + col] = v;
        }
    }
}

// ---------------- depthwise causal conv (K=4) + silu + dt softplus ----------------
__global__ __launch_bounds__(256) void k_conv(
    const float* __restrict__ proj, const float* __restrict__ cw,
    const float* __restrict__ cb, const float* __restrict__ dtbias,
    float* __restrict__ xBC, float* __restrict__ dtb)
{
    __shared__ float tile[19][512];
    int tt = blockIdx.x, b = blockIdx.y;
    int t0 = tt * 16;
    int tid = threadIdx.x;
    const float* prow = proj + (size_t)b*LSEQ*772;
    for (int f = tid; f < 19*256; f += 256) {
        int r = f >> 8, c2 = (f & 255) * 2;
        int t = t0 - 3 + r;
        float2 v = make_float2(0.f, 0.f);
        if (t >= 0 && t < LSEQ) v = *(const float2*)(prow + (size_t)t*772 + 256 + c2);
        *(float2*)&tile[r][c2] = v;
    }
    __syncthreads();
    int c0 = tid * 2;
    float w00 = cw[c0*4+0], w01 = cw[c0*4+1], w02 = cw[c0*4+2], w03 = cw[c0*4+3];
    float w10 = cw[c0*4+4], w11 = cw[c0*4+5], w12 = cw[c0*4+6], w13 = cw[c0*4+7];
    float cb0 = cb[c0], cb1 = cb[c0+1];
    for (int r = 0; r < 16; ++r) {
        int t = t0 + r;
        if (t >= LSEQ) break;
        float a0 = cb0, a1 = cb1;
        a0 = fmaf(tile[r  ][c0], w00, a0); a1 = fmaf(tile[r  ][c0+1], w10, a1);
        a0 = fmaf(tile[r+1][c0], w01, a0); a1 = fmaf(tile[r+1][c0+1], w11, a1);
        a0 = fmaf(tile[r+2][c0], w02, a0); a1 = fmaf(tile[r+2][c0+1], w12, a1);
        a0 = fmaf(tile[r+3][c0], w03, a0); a1 = fmaf(tile[r+3][c0+1], w13, a1);
        float2 o; o.x = siluf(a0); o.y = siluf(a1);
        *(float2*)(xBC + ((size_t)b*LSEQ + t)*512 + c0) = o;
    }
    if (tid < 64) {
        int r = tid >> 2, hh = tid & 3;
        int t = t0 + r;
        if (t < LSEQ) {
            float z = prow[(size_t)t*772 + 768 + hh] + dtbias[hh];
            float sp = fmaxf(z, 0.f) + log1pf(expf(-fabsf(z)));
            dtb[((size_t)b*LSEQ + t)*4 + hh] = sp;
        }
    }
}

// ---------------- SSD: per-chunk G = X^T diag(w) B, and chunk decay sums ----------------
__global__ __launch_bounds__(256) void k_ssd_pre(
    const float* __restrict__ xBC, const float* __restrict__ dtb,
    const float* __restrict__ A_log_l,
    float* __restrict__ G, float* __restrict__ asum)
{
    int c = blockIdx.x, hh = blockIdx.y, b = blockIdx.z;
    int t0g = c * 128;
    int q = LSEQ - t0g; if (q > 128) q = 128;
    int tid = threadIdx.x;
    __shared__ float sdt[128], sca[128], sw[128];
    __shared__ float sAsum;
    if (tid < 128) sdt[tid] = (tid < q) ? dtb[((size_t)b*LSEQ + t0g + tid)*4 + hh] : 0.f;
    __syncthreads();
    if (tid == 0) {
        float Ah = -expf(A_log_l[hh]);
        float run = 0.f;
        for (int s = 0; s < 128; ++s) { run += sdt[s]*Ah; sca[s] = run; }
        sAsum = run;
        asum[(b*NHC + hh)*NCH + c] = run;
    }
    __syncthreads();
    if (tid < 128) sw[tid] = expf(sAsum - sca[tid]) * sdt[tid];
    __syncthreads();

    __shared__ float Xs[32][68];
    __shared__ float Bs[32][132];
    int n0 = (tid & 31) * 4, p0 = (tid >> 5) * 8;
    float acc[8][4] = {};
    const float* xrow = xBC + ((size_t)b*LSEQ + t0g) * 512;
    for (int st = 0; st < 4; ++st) {
        #pragma unroll
        for (int r = 0; r < 2; ++r) {
            int idx = tid + r*256;
            int s = idx >> 4, p4 = (idx & 15)*4;
            int sg = st*32 + s;
            float4 v = make_float4(0.f,0.f,0.f,0.f);
            if (sg < q) v = *(const float4*)(xrow + (size_t)sg*512 + hh*64 + p4);
            float wv = sw[sg];
            Xs[s][p4] = v.x*wv; Xs[s][p4+1] = v.y*wv; Xs[s][p4+2] = v.z*wv; Xs[s][p4+3] = v.w*wv;
        }
        #pragma unroll
        for (int r = 0; r < 4; ++r) {
            int idx = tid + r*256;
            int s = idx >> 5, n4 = (idx & 31)*4;
            int sg = st*32 + s;
            float4 v = make_float4(0.f,0.f,0.f,0.f);
            if (sg < q) v = *(const float4*)(xrow + (size_t)sg*512 + 256 + n4);
            *(float4*)&Bs[s][n4] = v;
        }
        __syncthreads();
        #pragma unroll 8
        for (int ss = 0; ss < 32; ++ss) {
            float4 x0 = *(const float4*)&Xs[ss][p0];
            float4 x1 = *(const float4*)&Xs[ss][p0+4];
            float xv[8] = {x0.x,x0.y,x0.z,x0.w,x1.x,x1.y,x1.z,x1.w};
            float4 bq = *(const float4*)&Bs[ss][n0];
            float bv[4] = {bq.x,bq.y,bq.z,bq.w};
            #pragma unroll
            for (int i = 0; i < 8; ++i)
                #pragma unroll
                for (int j = 0; j < 4; ++j)
                    acc[i][j] = fmaf(xv[i], bv[j], acc[i][j]);
        }
        __syncthreads();
    }
    size_t gbase = (((size_t)(b*NHC + hh))*NCH + c) * 8192;
    #pragma unroll
    for (int i = 0; i < 8; ++i) {
        float4 v; v.x = acc[i][0]; v.y = acc[i][1]; v.z = acc[i][2]; v.w = acc[i][3];
        *(float4*)(G + gbase + (size_t)(p0+i)*128 + n0) = v;
    }
}

// ---------------- SSD: chunk-level state recurrence ----------------
__global__ __launch_bounds__(256) void k_ssd_state(
    const float* __restrict__ G, const float* __restrict__ asum, float* __restrict__ Sinit)
{
    __shared__ float eA[NCH];
    int slice = blockIdx.x, bh = blockIdx.y;
    int tid = threadIdx.x;
    if (tid < NCH) eA[tid] = expf(asum[bh*NCH + tid]);
    __syncthreads();
    size_t base = (size_t)bh * NCH * 8192 + slice*1024 + tid*4;
    float s0=0.f, s1=0.f, s2=0.f, s3=0.f;
    for (int c = 0; c < NCH; ++c) {
        size_t off = base + (size_t)c*8192;
        float4 o; o.x=s0; o.y=s1; o.z=s2; o.w=s3;
        *(float4*)(Sinit + off) = o;
        float4 g = *(const float4*)(G + off);
        float da = eA[c];
        s0 = fmaf(s0, da, g.x); s1 = fmaf(s1, da, g.y);
        s2 = fmaf(s2, da, g.z); s3 = fmaf(s3, da, g.w);
    }
}

// ---------------- SSD: per-chunk output (intra scores + inter state) ----------------
__global__ __launch_bounds__(256) void k_ssd_out(
    const float* __restrict__ xBC, const float* __restrict__ dtb,
    const float* __restrict__ Sinit, const float* __restrict__ A_log_l,
    const float* __restrict__ D_l, float* __restrict__ y)
{
    __shared__ float sm[12800 + 256];
    float* sdt = sm + 12800;
    float* sca = sdt + 128;
    float* Bn = sm;             // phase A
    float* Cn = sm + 4224;
    float* Sn = sm + 8448;
    float* S  = sm;             // phase B
    float* Xs = sm + 8448;

    int c = blockIdx.x, hh = blockIdx.y, b = blockIdx.z;
    int t0g = c * 128;
    int q = LSEQ - t0g; if (q > 128) q = 128;
    int tid = threadIdx.x;
    if (tid < 128) sdt[tid] = (tid < q) ? dtb[((size_t)b*LSEQ + t0g + tid)*4 + hh] : 0.f;
    __syncthreads();
    if (tid == 0) {
        float Ah = -expf(A_log_l[hh]);
        float run = 0.f;
        for (int s = 0; s < 128; ++s) { run += sdt[s]*Ah; sca[s] = run; }
    }
    __syncthreads();

    int t0 = (tid >> 3) * 4;
    int s0 = (tid & 7) * 16;
    int p0 = (tid & 7) * 8;

    float acc[4][16] = {};
    float iacc[4][8] = {};
    const float* xrow = xBC + ((size_t)b*LSEQ + t0g) * 512;
    size_t sibase = (((size_t)(b*NHC + hh))*NCH + c) * 8192;

    for (int nt = 0; nt < 4; ++nt) {
        #pragma unroll
        for (int r = 0; r < 4; ++r) {
            int idx = tid + r*256;
            int s = idx >> 3, nn4 = (idx & 7) * 4;
            float4 vb = make_float4(0.f,0.f,0.f,0.f), vc = vb;
            if (s < q) {
                vb = *(const float4*)(xrow + (size_t)s*512 + 256 + nt*32 + nn4);
                vc = *(const float4*)(xrow + (size_t)s*512 + 384 + nt*32 + nn4);
            }
            Bn[(nn4+0)*132 + s] = vb.x; Bn[(nn4+1)*132 + s] = vb.y;
            Bn[(nn4+2)*132 + s] = vb.z; Bn[(nn4+3)*132 + s] = vb.w;
            Cn[(nn4+0)*132 + s] = vc.x; Cn[(nn4+1)*132 + s] = vc.y;
            Cn[(nn4+2)*132 + s] = vc.z; Cn[(nn4+3)*132 + s] = vc.w;
        }
        #pragma unroll
        for (int r = 0; r < 2; ++r) {
            int idx = tid + r*256;
            int p = idx >> 3, nn4 = (idx & 7) * 4;
            float4 v = *(const float4*)(Sinit + sibase + (size_t)p*128 + nt*32 + nn4);
            Sn[(nn4+0)*68 + p] = v.x; Sn[(nn4+1)*68 + p] = v.y;
            Sn[(nn4+2)*68 + p] = v.z; Sn[(nn4+3)*68 + p] = v.w;
        }
        __syncthreads();
        #pragma unroll 2
        for (int nn = 0; nn < 32; ++nn) {
            float4 cq = *(const float4*)&Cn[nn*132 + t0];
            float cv[4] = {cq.x, cq.y, cq.z, cq.w};
            float bb[16];
            float4 b0 = *(const float4*)&Bn[nn*132 + s0];
            float4 b1 = *(const float4*)&Bn[nn*132 + s0 + 4];
            float4 b2 = *(const float4*)&Bn[nn*132 + s0 + 8];
            float4 b3 = *(const float4*)&Bn[nn*132 + s0 + 12];
            bb[0]=b0.x; bb[1]=b0.y; bb[2]=b0.z; bb[3]=b0.w;
            bb[4]=b1.x; bb[5]=b1.y; bb[6]=b1.z; bb[7]=b1.w;
            bb[8]=b2.x; bb[9]=b2.y; bb[10]=b2.z; bb[11]=b2.w;
            bb[12]=b3.x; bb[13]=b3.y; bb[14]=b3.z; bb[15]=b3.w;
            float sv[8];
            float4 s0v = *(const float4*)&Sn[nn*68 + p0];
            float4 s1v = *(const float4*)&Sn[nn*68 + p0 + 4];
            sv[0]=s0v.x; sv[1]=s0v.y; sv[2]=s0v.z; sv[3]=s0v.w;
            sv[4]=s1v.x; sv[5]=s1v.y; sv[6]=s1v.z; sv[7]=s1v.w;
            #pragma unroll
            for (int i = 0; i < 4; ++i) {
                #pragma unroll
                for (int j = 0; j < 16; ++j) acc[i][j] = fmaf(cv[i], bb[j], acc[i][j]);
                #pragma unroll
                for (int j = 0; j < 8; ++j) iacc[i][j] = fmaf(cv[i], sv[j], iacc[i][j]);
            }
        }
        __syncthreads();
    }

    float yacc[4][8];
    #pragma unroll
    for (int i = 0; i < 4; ++i) {
        float e = expf(sca[t0+i]);
        #pragma unroll
        for (int j = 0; j < 8; ++j) yacc[i][j] = iacc[i][j] * e;
    }
    float Dh = D_l[hh];

    for (int half = 0; half < 2; ++half) {
        int sb = half * 64;
        if ((s0 >> 6) == half) {
            #pragma unroll
            for (int i = 0; i < 4; ++i) {
                int t = t0 + i;
                float cat = sca[t];
                #pragma unroll
                for (int j = 0; j < 16; ++j) {
                    int s = s0 + j;
                    float val = 0.f;
                    if (s <= t && t < q) val = acc[i][j] * expf(cat - sca[s]) * sdt[s];
                    S[(s - sb)*132 + t] = val;
                }
            }
        }
        #pragma unroll
        for (int r = 0; r < 4; ++r) {
            int idx = tid + r*256;
            int sl = idx >> 4, p4 = (idx & 15) * 4;
            int s = sb + sl;
            float4 v = make_float4(0.f,0.f,0.f,0.f);
            if (s < q) v = *(const float4*)(xrow + (size_t)s*512 + hh*64 + p4);
            *(float4*)&Xs[sl*68 + p4] = v;
        }
        __syncthreads();
        if ((t0 >> 6) == half) {
            #pragma unroll
            for (int i = 0; i < 4; ++i) {
                int t = t0 + i;
                if (t < q) {
                    #pragma unroll
                    for (int j = 0; j < 8; ++j)
                        yacc[i][j] = fmaf(Dh, Xs[(t - sb)*68 + p0 + j], yacc[i][j]);
                }
            }
        }
        #pragma unroll 4
        for (int sl = 0; sl < 64; ++sl) {
            float4 sq = *(const float4*)&S[sl*132 + t0];
            float sc[4] = {sq.x, sq.y, sq.z, sq.w};
            float4 x0 = *(const float4*)&Xs[sl*68 + p0];
            float4 x1 = *(const float4*)&Xs[sl*68 + p0 + 4];
            float xv[8] = {x0.x,x0.y,x0.z,x0.w,x1.x,x1.y,x1.z,x1.w};
            #pragma unroll
            for (int i = 0; i < 4; ++i)
                #pragma unroll
                for (int j = 0; j < 8; ++j)
                    yacc[i][j] = fmaf(sc[i], xv[j], yacc[i][j]);
        }
        __syncthreads();
    }

    #pragma unroll
    for (int i = 0; i < 4; ++i) {
        int t = t0 + i;
        if (t < q) {
            float* yp = y + ((size_t)b*LSEQ + t0g + t)*256 + hh*64 + p0;
            float4 w0; w0.x=yacc[i][0]; w0.y=yacc[i][1]; w0.z=yacc[i][2]; w0.w=yacc[i][3];
            float4 w1; w1.x=yacc[i][4]; w1.y=yacc[i][5]; w1.z=yacc[i][6]; w1.w=yacc[i][7];
            *(float4*)yp = w0; *(float4*)(yp+4) = w1;
        }
    }
}

// ---------------- gate (silu) + rmsnorm dim=256 (wave per row), bf16 out ----------------
__global__ __launch_bounds__(256) void k_gatenorm(
    const float* __restrict__ y, const float* __restrict__ proj,
    const float* __restrict__ gnw, unsigned short* __restrict__ out)
{
    int tid = threadIdx.x; int lane = tid & 63; int wv = tid >> 6;
    size_t row = (size_t)blockIdx.x*4 + wv;
    float4 yv = *(const float4*)(y + row*256 + lane*4);
    float4 gv = *(const float4*)(proj + row*772 + lane*4);
    float v0 = yv.x * siluf(gv.x);
    float v1 = yv.y * siluf(gv.y);
    float v2 = yv.z * siluf(gv.z);
    float v3 = yv.w * siluf(gv.w);
    float ss = v0*v0 + v1*v1 + v2*v2 + v3*v3;
    #pragma unroll
    for (int off = 32; off; off >>= 1) ss += __shfl_xor(ss, off);
    float sc = rsqrtf(ss*(1.f/256.f) + 1e-5f);
    float4 wv4 = *(const float4*)(gnw + lane*4);
    ushort4 o;
    o.x = f2bf(v0*sc*wv4.x); o.y = f2bf(v1*sc*wv4.y);
    o.z = f2bf(v2*sc*wv4.z); o.w = f2bf(v3*sc*wv4.w);
    *(ushort4*)(out + row*256 + lane*4) = o;
}

// ---------------- directional recombine ----------------
__global__ __launch_bounds__(256) void k_combine(
    const float* __restrict__ hn, float* __restrict__ xm, int total)
{
    int idx = blockIdx.x*256 + threadIdx.x;
    if (idx >= total) return;
    int d4 = idx & 31; int r = idx >> 5; int l = r % 1530; int b = r / 1530;
    int hg = l / 90, wg = l - hg*90; int l1 = wg*17 + hg;
    size_t base = (size_t)b * LSEQ;
    float4 a0 = *(const float4*)(hn + (base + l)*128 + d4*4);
    float4 a1 = *(const float4*)(hn + (base + LIMG + l1)*128 + d4*4);
    float4 a2 = *(const float4*)(hn + (base + 2*LIMG + (LIMG-1-l))*128 + d4*4);
    float4 a3 = *(const float4*)(hn + (base + 3*LIMG + (LIMG-1-l1))*128 + d4*4);
    float4 o; o.x = a0.x+a1.x+a2.x+a3.x; o.y = a0.y+a1.y+a2.y+a3.y;
    o.z = a0.z+a1.z+a2.z+a3.z; o.w = a0.w+a1.w+a2.w+a3.w;
    *(float4*)(xm + ((size_t)b*LIMG + l)*128 + d4*4) = o;
}

// ---------------- un-patchify scatter ----------------
__global__ __launch_bounds__(256) void k_unpatch(
    const float* __restrict__ rbuf, float* __restrict__ out, int total)
{
    int idx = blockIdx.x*256 + threadIdx.x;
    if (idx >= total) return;
    int addr = idx*4;
    int col = addr % 720; int t = addr / 720; int row = t % 340; t /= 340;
    int cc = t % 3; int b = t / 3;
    int hg = row/20, ii = row - hg*20, wg = col >> 3, j0 = col & 7;
    size_t rb = ((size_t)(b*LIMG) + hg*90 + wg)*480 + ii*24 + cc;
    float4 v;
    v.x = rbuf[rb + (j0+0)*3];
    v.y = rbuf[rb + (j0+1)*3];
    v.z = rbuf[rb + (j0+2)*3];
    v.w = rbuf[rb + (j0+3)*3];
    *(float4*)(out + addr) = v;
}

extern "C" void kernel_launch(void* const* d_in, const int* in_sizes, int n_in,
                              void* d_out, int out_size, void* d_ws, size_t ws_size,
                              hipStream_t stream) {
    (void)in_sizes; (void)n_in;
    const float* x      = (const float*)d_in[0];
    const float* W_pe   = (const float*)d_in[1];
    const float* b_pe   = (const float*)d_in[2];
    const float* norm_w = (const float*)d_in[3];
    const float* in_w   = (const float*)d_in[4];
    const float* in_b   = (const float*)d_in[5];
    const float* conv_w = (const float*)d_in[6];
    const float* conv_b = (const float*)d_in[7];
    const float* dt_bias= (const float*)d_in[8];
    const float* A_log  = (const float*)d_in[9];
    const float* Dp     = (const float*)d_in[10];
    const float* gn_w   = (const float*)d_in[11];
    const float* out_w  = (const float*)d_in[12];
    const float* out_b  = (const float*)d_in[13];
    const float* normf_w= (const float*)d_in[14];
    const float* r1_w   = (const float*)d_in[15];
    const float* r1_b   = (const float*)d_in[16];
    const float* r2_w   = (const float*)d_in[17];
    const float* r2_b   = (const float*)d_in[18];

    auto needed = [](int Bc) -> size_t {
        size_t o = 0;
        auto al = [&](size_t n){ o += (n + 63) & ~(size_t)63; };
        al((size_t)Bc*LSEQ*128);       // h (also hnb bf16)
        al((size_t)Bc*LSEQ*128);       // hn f32 (final) — separate from h
        al((size_t)Bc*LSEQ*772);       // proj (also xm/t1/rbuf)
        al((size_t)Bc*LSEQ*512);       // xbc (also ynb bf16)
        al((size_t)Bc*LSEQ*4);         // dtb
        al((size_t)Bc*NHC*NCH*8192);   // G (also ybuf)
        al((size_t)Bc*NHC*NCH*8192);   // Sinit
        al((size_t)Bc*NHC*NCH);        // asum
        al(229376);                    // inwB bf16 (458752 ush)
        al(65536);                     // outwB bf16 (131072 ush)
        al(16384); al(61440); al(61440);
        return o * 4;
    };
    int Bc = 0;
    const int cands[4] = {8, 4, 2, 1};
    for (int i = 0; i < 4; ++i) if (needed(cands[i]) <= ws_size) { Bc = cands[i]; break; }
    if (Bc == 0) {
        float mv = (float)((double)ws_size / (1024.0*1024.0));
        k_marker<<<(out_size+255)/256, 256, 0, stream>>>((float*)d_out, out_size, mv);
        return;
    }

    float* ws = (float*)d_ws;
    size_t o = 0;
    auto alloc = [&](size_t n){ size_t r = o; o += (n + 63) & ~(size_t)63; return r; };
    float* h     = ws + alloc((size_t)Bc*LSEQ*128);
    float* hn    = ws + alloc((size_t)Bc*LSEQ*128);
    float* proj  = ws + alloc((size_t)Bc*LSEQ*772);
    float* xbc   = ws + alloc((size_t)Bc*LSEQ*512);
    float* dtb   = ws + alloc((size_t)Bc*LSEQ*4);
    float* G     = ws + alloc((size_t)Bc*NHC*NCH*8192);
    float* Sini  = ws + alloc((size_t)Bc*NHC*NCH*8192);
    float* asum  = ws + alloc((size_t)Bc*NHC*NCH);
    unsigned short* inwB  = (unsigned short*)(ws + alloc(229376));
    unsigned short* outwB = (unsigned short*)(ws + alloc(65536));
    float* r1T   = ws + alloc(16384);
    float* r2T   = ws + alloc(61440);
    float* peT   = ws + alloc(61440);
    float* ybuf  = G;                               // G dead after k_ssd_state
    unsigned short* hnb  = (unsigned short*)hn;     // bf16 norm for layers (hn f32 only for final)
    unsigned short* ynb  = (unsigned short*)xbc;    // xbc dead after k_ssd_out
    float* xm    = proj;                            // proj dead after last gatenorm
    float* t1    = proj + (size_t)Bc*LIMG*128;
    float* rbuf  = t1 + (size_t)Bc*LIMG*128;

    k_wtrans<<<1792, 256, 0, stream>>>(W_pe, in_w, out_w, r1_w, r2_w, peT, inwB, outwB, r1T, r2T);

    for (int bc = 0; bc < 8; bc += Bc) {
        const float* xc = x + (size_t)bc*3*340*720;
        float* outc = (float*)d_out + (size_t)bc*3*340*720;
        int rowsL = Bc*LSEQ;
        int rowsI = Bc*LIMG;
        int npatch = Bc*LIMG;
        int mb128 = (rowsL + 127) / 128;
        int mbI = (rowsI + 63) / 64;

        k_embed2<<<(npatch + 31)/32, 256, 0, stream>>>(xc, peT, b_pe, h, npatch);
        for (int l = 0; l < 4; ++l) {
            k_rms128<1><<<(rowsL + 3)/4, 256, 0, stream>>>(h, norm_w + l*128, hnb, rowsL);
            k_bgemm<0><<<dim3(mb128, 7), 256, 0, stream>>>(hnb, inwB + (size_t)l*114688,
                                                           in_b + l*772, proj, 772,
                                                           rowsL, 772, 128);
            k_conv<<<dim3(383, Bc), 256, 0, stream>>>(proj, conv_w + l*2048, conv_b + l*512,
                                                      dt_bias + l*4, xbc, dtb);
            k_ssd_pre<<<dim3(NCH, NHC, Bc), 256, 0, stream>>>(xbc, dtb, A_log + l*4, G, asum);
            k_ssd_state<<<dim3(8, Bc*NHC), 256, 0, stream>>>(G, asum, Sini);
            k_ssd_out<<<dim3(NCH, NHC, Bc), 256, 0, stream>>>(xbc, dtb, Sini, A_log + l*4,
                                                              Dp + l*4, ybuf);
            k_gatenorm<<<rowsL/4, 256, 0, stream>>>(ybuf, proj, gn_w + l*256, ynb);
            k_bgemm<2><<<dim3(mb128, 1), 256, 0, stream>>>(ynb, outwB + (size_t)l*32768,
                                                           out_b + l*128, h, 128,
                                                           rowsL, 128, 256);
        }
        k_rms128<0><<<(rowsL + 3)/4, 256, 0, stream>>>(h, normf_w, hn, rowsL);
        k_combine<<<(rowsI*32 + 255)/256, 256, 0, stream>>>(hn, xm, rowsI*32);
        k_gemm<1><<<dim3(mbI, 2), 256, 0, stream>>>(xm, 128, r1T, 128, r1_b, t1, 128, rowsI, 128, 128);
        k_gemm<0><<<dim3(mbI, 8), 256, 0, stream>>>(t1, 128, r2T, 480, r2_b, rbuf, 480, rowsI, 480, 128);
        k_unpatch<<<(Bc*183600 + 255)/256, 256, 0, stream>>>(rbuf, outc, Bc*183600);
    }
}

// Round 6
// 1819.279 us; speedup vs baseline: 1.7556x; 1.2428x over previous
//
#include <hip/hip_runtime.h>

#define LSEQ 6120
#define LIMG 1530
#define NCH  48      // chunks of 128
#define NHC  4

typedef __attribute__((ext_vector_type(8))) short bf8_t;   // 8 bf16 in 4 VGPRs
typedef __attribute__((ext_vector_type(4))) float f32x4;

__device__ __forceinline__ float siluf(float v) { return v / (1.f + expf(-v)); }
__device__ __forceinline__ unsigned short f2bf(float f) {
    unsigned u = __builtin_bit_cast(unsigned, f);
    unsigned r = (u + 0x7FFFu + ((u >> 16) & 1u)) >> 16;
    return (unsigned short)r;
}
__device__ __forceinline__ ushort4 f4bf(float4 v) {
    ushort4 o; o.x = f2bf(v.x); o.y = f2bf(v.y); o.z = f2bf(v.z); o.w = f2bf(v.w); return o;
}

__global__ __launch_bounds__(256) void k_marker(float* out, int n, float val) {
    int i = blockIdx.x*256 + threadIdx.x;
    if (i < n) out[i] = val;
}

// ---------------- weight prep: peT/r1T/r2T f32 transposes + bf16 converts ----------------
__global__ __launch_bounds__(256) void k_wtrans(
    const float* __restrict__ W_pe, const float* __restrict__ in_w,
    const float* __restrict__ out_w, const float* __restrict__ r1_w,
    const float* __restrict__ r2_w,
    float* __restrict__ peT, unsigned short* __restrict__ inwB,
    unsigned short* __restrict__ outwB,
    float* __restrict__ r1T, float* __restrict__ r2T)
{
    int idx = blockIdx.x * 256 + threadIdx.x;
    if (idx < 480*128) { int e = idx >> 7, d = idx & 127; peT[idx] = W_pe[d*480 + e]; }
    if (idx < 4*896*128) {          // bf16 [l][n<896][k], zero-pad n>=772
        int l = idx / 114688; int r = idx - l*114688; int n = r >> 7; int k = r & 127;
        inwB[idx] = (n < 772) ? f2bf(in_w[l*98816 + n*128 + k]) : (unsigned short)0;
    }
    if (idx < 4*128*256) outwB[idx] = f2bf(out_w[idx]);   // natural [l][n=128][k=256]
    if (idx < 128*128) { int k = idx >> 7, n = idx & 127; r1T[idx] = r1_w[(n<<7) + k]; }
    if (idx < 128*480) { int k = idx / 480, n = idx - k*480; r2T[idx] = r2_w[(n<<7) + k]; }
}

// ---------------- patch embed as tiled GEMM + 4-directional scatter ----------------
__global__ __launch_bounds__(256) void k_embed2(
    const float* __restrict__ x, const float* __restrict__ peT,
    const float* __restrict__ b_pe, float* __restrict__ h, int npatch)
{
    __shared__ float xs[32][36];
    __shared__ float ps[32][128];
    int tid = threadIdx.x;
    int pbase = blockIdx.x * 32;
    int m0 = (tid >> 4) * 2;
    int n0 = (tid & 15) * 8;
    float acc[2][8] = {};
    for (int kt = 0; kt < 480; kt += 32) {
        #pragma unroll
        for (int r = 0; r < 4; ++r) {
            int idx = tid + r*256;
            int k = idx >> 5, n4 = (idx & 31) * 4;
            *(float4*)&ps[k][n4] = *(const float4*)(peT + (size_t)(kt + k)*128 + n4);
        }
        {
            int pp = tid >> 3, e0 = (tid & 7) * 4;
            int pid = pbase + pp;
            float4 v = make_float4(0.f,0.f,0.f,0.f);
            if (pid < npatch) {
                int e = kt + e0;
                int wg = pid % 90; int t = pid / 90; int hg = t % 17; int b = t / 17;
                int cc = e / 160; int r2 = e - cc*160; int rr = r2 >> 3; int jj = r2 & 7;
                v = *(const float4*)(x + ((size_t)(b*3 + cc)*340 + hg*20 + rr)*720 + wg*8 + jj);
            }
            *(float4*)&xs[pp][e0] = v;
        }
        __syncthreads();
        #pragma unroll 4
        for (int k = 0; k < 32; ++k) {
            float a0 = xs[m0][k], a1 = xs[m0+1][k];
            float4 b0 = *(const float4*)&ps[k][n0];
            float4 b1 = *(const float4*)&ps[k][n0+4];
            float bv[8] = {b0.x,b0.y,b0.z,b0.w,b1.x,b1.y,b1.z,b1.w};
            #pragma unroll
            for (int j = 0; j < 8; ++j) {
                acc[0][j] = fmaf(a0, bv[j], acc[0][j]);
                acc[1][j] = fmaf(a1, bv[j], acc[1][j]);
            }
        }
        __syncthreads();
    }
    #pragma unroll
    for (int i = 0; i < 2; ++i) {
        int pid = pbase + m0 + i;
        if (pid >= npatch) continue;
        int wg = pid % 90; int t = pid / 90; int hg = t % 17; int b = t / 17;
        int l0 = hg*90 + wg, l1 = wg*17 + hg;
        size_t hb = (size_t)b * LSEQ;
        float o[8];
        #pragma unroll
        for (int j = 0; j < 8; ++j) o[j] = acc[i][j] + b_pe[n0 + j];
        float4 w0; w0.x=o[0]; w0.y=o[1]; w0.z=o[2]; w0.w=o[3];
        float4 w1; w1.x=o[4]; w1.y=o[5]; w1.z=o[6]; w1.w=o[7];
        float* p;
        p = h + (hb + l0)*128 + n0;                       *(float4*)p = w0; *(float4*)(p+4) = w1;
        p = h + (hb + LIMG + l1)*128 + n0;                *(float4*)p = w0; *(float4*)(p+4) = w1;
        p = h + (hb + 2*LIMG + (LIMG-1-l0))*128 + n0;     *(float4*)p = w0; *(float4*)(p+4) = w1;
        p = h + (hb + 3*LIMG + (LIMG-1-l1))*128 + n0;     *(float4*)p = w0; *(float4*)(p+4) = w1;
    }
}

// ---------------- rmsnorm dim=128 (wave per row), f32 or bf16 out ----------------
template<int OBF>
__global__ __launch_bounds__(256) void k_rms128(
    const float* __restrict__ in, const float* __restrict__ w,
    void* __restrict__ out, int nrows)
{
    int tid = threadIdx.x; int lane = tid & 63; int wv = tid >> 6;
    int row = blockIdx.x*4 + wv;
    if (row >= nrows) return;
    const float* xr = in + (size_t)row*128;
    float2 xv = *(const float2*)(xr + lane*2);
    float ss = xv.x*xv.x + xv.y*xv.y;
    #pragma unroll
    for (int off = 32; off; off >>= 1) ss += __shfl_xor(ss, off);
    float sc = rsqrtf(ss*(1.f/128.f) + 1e-5f);
    float2 wv2 = *(const float2*)(w + lane*2);
    float2 o; o.x = xv.x*sc*wv2.x; o.y = xv.y*sc*wv2.y;
    if (OBF) {
        ushort2 st; st.x = f2bf(o.x); st.y = f2bf(o.y);
        *(ushort2*)((unsigned short*)out + (size_t)row*128 + lane*2) = st;
    } else {
        *(float2*)((float*)out + (size_t)row*128 + lane*2) = o;
    }
}

// ---------------- bf16 MFMA GEMM: C[M,N] = A[M,K] @ W[N,K]^T (+bias, epi) ----------------
template<int EPI>
__global__ __launch_bounds__(256) void k_bgemm(
    const unsigned short* __restrict__ A,
    const unsigned short* __restrict__ W,
    const float* __restrict__ bias,
    float* __restrict__ C, int ldc,
    int M, int N, int Ktot)
{
    __shared__ unsigned short Al[128][72];
    __shared__ unsigned short Wl[128][72];
    int tid = threadIdx.x;
    int mbase = blockIdx.x * 128, nbase = blockIdx.y * 128;
    int lane = tid & 63, wv = tid >> 6;
    int wm = (wv >> 1) * 64, wn = (wv & 1) * 64;
    int fr = lane & 15;
    int fq = lane >> 4;
    f32x4 acc[4][4] = {};

    int srow = tid >> 1, sseg = tid & 1;
    bool aok = (mbase + srow) < M;
    const unsigned short* ap = A + (size_t)(mbase + srow)*Ktot + sseg*32;
    const unsigned short* wp = W + (size_t)(nbase + srow)*Ktot + sseg*32;

    for (int kt = 0; kt < Ktot; kt += 64) {
        #pragma unroll
        for (int u = 0; u < 4; ++u) {
            bf8_t v = {};
            if (aok) v = *(const bf8_t*)(ap + kt + u*8);
            *(bf8_t*)&Al[srow][sseg*32 + u*8] = v;
        }
        #pragma unroll
        for (int u = 0; u < 4; ++u) {
            bf8_t v = *(const bf8_t*)(wp + kt + u*8);
            *(bf8_t*)&Wl[srow][sseg*32 + u*8] = v;
        }
        __syncthreads();
        #pragma unroll
        for (int ks = 0; ks < 2; ++ks) {
            bf8_t af[4], wf[4];
            #pragma unroll
            for (int i = 0; i < 4; ++i)
                af[i] = *(const bf8_t*)&Al[wm + i*16 + fr][ks*32 + fq*8];
            #pragma unroll
            for (int j = 0; j < 4; ++j)
                wf[j] = *(const bf8_t*)&Wl[wn + j*16 + fr][ks*32 + fq*8];
            #pragma unroll
            for (int i = 0; i < 4; ++i)
                #pragma unroll
                for (int j = 0; j < 4; ++j)
                    acc[i][j] = __builtin_amdgcn_mfma_f32_16x16x32_bf16(af[i], wf[j], acc[i][j], 0, 0, 0);
        }
        __syncthreads();
    }
    #pragma unroll
    for (int j = 0; j < 4; ++j) {
        int col = nbase + wn + j*16 + fr;
        if (col >= N) continue;
        float bv = bias[col];
        #pragma unroll
        for (int i = 0; i < 4; ++i) {
            int row0 = mbase + wm + i*16 + fq*4;
            #pragma unroll
            for (int r = 0; r < 4; ++r) {
                int row = row0 + r;
                if (row < M) {
                    float v = acc[i][j][r] + bv;
                    if (EPI == 2) v += C[(size_t)row*ldc + col];
                    C[(size_t)row*ldc + col] = v;
                }
            }
        }
    }
}

// ---------------- generic f32 GEMM (MLP only) ----------------
template<int EPI>
__global__ __launch_bounds__(256) void k_gemm(
    const float* __restrict__ A, int lda,
    const float* __restrict__ W, int ldw,
    const float* __restrict__ bias,
    float* __restrict__ C, int ldc,
    int M, int N, int Ktot)
{
    __shared__ float As[64][65];
    __shared__ float Bs[64][64];
    int tid = threadIdx.x;
    int mbase = blockIdx.x * 64, nbase = blockIdx.y * 64;
    int m0 = (tid & 15) * 4, n0 = (tid >> 4) * 4;
    float acc[4][4] = {};
    bool fullN = (nbase + 64 <= N);
    for (int kt = 0; kt < Ktot; kt += 64) {
        #pragma unroll
        for (int r = 0; r < 4; ++r) {
            int idx = tid + r*256;
            int m = idx >> 4, k4 = (idx & 15) * 4;
            int row = mbase + m;
            float4 v = make_float4(0.f,0.f,0.f,0.f);
            if (row < M) v = *(const float4*)(A + (size_t)row*lda + kt + k4);
            As[m][k4] = v.x; As[m][k4+1] = v.y; As[m][k4+2] = v.z; As[m][k4+3] = v.w;
        }
        #pragma unroll
        for (int r = 0; r < 4; ++r) {
            int idx = tid + r*256;
            int k = idx >> 4, n4 = (idx & 15) * 4;
            const float* wp = W + (size_t)(kt + k)*ldw + nbase + n4;
            float4 v;
            if (fullN) v = *(const float4*)wp;
            else {
                int col = nbase + n4;
                v.x = (col   < N) ? wp[0] : 0.f;
                v.y = (col+1 < N) ? wp[1] : 0.f;
                v.z = (col+2 < N) ? wp[2] : 0.f;
                v.w = (col+3 < N) ? wp[3] : 0.f;
            }
            *(float4*)&Bs[k][n4] = v;
        }
        __syncthreads();
        #pragma unroll 8
        for (int k = 0; k < 64; ++k) {
            float av[4];
            av[0] = As[m0][k]; av[1] = As[m0+1][k]; av[2] = As[m0+2][k]; av[3] = As[m0+3][k];
            float4 bq = *(const float4*)&Bs[k][n0];
            float bv[4] = {bq.x, bq.y, bq.z, bq.w};
            #pragma unroll
            for (int i = 0; i < 4; ++i)
                #pragma unroll
                for (int j = 0; j < 4; ++j)
                    acc[i][j] = fmaf(av[i], bv[j], acc[i][j]);
        }
        __syncthreads();
    }
    #pragma unroll
    for (int i = 0; i < 4; ++i) {
        int row = mbase + m0 + i;
        if (row >= M) continue;
        #pragma unroll
        for (int j = 0; j < 4; ++j) {
            int col = nbase + n0 + j;
            if (col >= N) continue;
            float v = acc[i][j] + bias[col];
            if (EPI == 1) v = 0.5f * v * (1.f + erff(v * 0.70710678118654752f));
            C[(size_t)row*ldc + col] = v;
        }
    }
}

// ---------------- depthwise causal conv (K=4) + silu + dt softplus ----------------
__global__ __launch_bounds__(256) void k_conv(
    const float* __restrict__ proj, const float* __restrict__ cw,
    const float* __restrict__ cb, const float* __restrict__ dtbias,
    float* __restrict__ xBC, float* __restrict__ dtb)
{
    __shared__ float tile[19][512];
    int tt = blockIdx.x, b = blockIdx.y;
    int t0 = tt * 16;
    int tid = threadIdx.x;
    const float* prow = proj + (size_t)b*LSEQ*772;
    for (int f = tid; f < 19*256; f += 256) {
        int r = f >> 8, c2 = (f & 255) * 2;
        int t = t0 - 3 + r;
        float2 v = make_float2(0.f, 0.f);
        if (t >= 0 && t < LSEQ) v = *(const float2*)(prow + (size_t)t*772 + 256 + c2);
        *(float2*)&tile[r][c2] = v;
    }
    __syncthreads();
    int c0 = tid * 2;
    float w00 = cw[c0*4+0], w01 = cw[c0*4+1], w02 = cw[c0*4+2], w03 = cw[c0*4+3];
    float w10 = cw[c0*4+4], w11 = cw[c0*4+5], w12 = cw[c0*4+6], w13 = cw[c0*4+7];
    float cb0 = cb[c0], cb1 = cb[c0+1];
    for (int r = 0; r < 16; ++r) {
        int t = t0 + r;
        if (t >= LSEQ) break;
        float a0 = cb0, a1 = cb1;
        a0 = fmaf(tile[r  ][c0], w00, a0); a1 = fmaf(tile[r  ][c0+1], w10, a1);
        a0 = fmaf(tile[r+1][c0], w01, a0); a1 = fmaf(tile[r+1][c0+1], w11, a1);
        a0 = fmaf(tile[r+2][c0], w02, a0); a1 = fmaf(tile[r+2][c0+1], w12, a1);
        a0 = fmaf(tile[r+3][c0], w03, a0); a1 = fmaf(tile[r+3][c0+1], w13, a1);
        float2 o; o.x = siluf(a0); o.y = siluf(a1);
        *(float2*)(xBC + ((size_t)b*LSEQ + t)*512 + c0) = o;
    }
    if (tid < 64) {
        int r = tid >> 2, hh = tid & 3;
        int t = t0 + r;
        if (t < LSEQ) {
            float z = prow[(size_t)t*772 + 768 + hh] + dtbias[hh];
            float sp = fmaxf(z, 0.f) + log1pf(expf(-fabsf(z)));
            dtb[((size_t)b*LSEQ + t)*4 + hh] = sp;
        }
    }
}

// ---------------- SSD: per-chunk G = X^T diag(w) B, and chunk decay sums ----------------
__global__ __launch_bounds__(256) void k_ssd_pre(
    const float* __restrict__ xBC, const float* __restrict__ dtb,
    const float* __restrict__ A_log_l,
    float* __restrict__ G, float* __restrict__ asum)
{
    int c = blockIdx.x, hh = blockIdx.y, b = blockIdx.z;
    int t0g = c * 128;
    int q = LSEQ - t0g; if (q > 128) q = 128;
    int tid = threadIdx.x;
    __shared__ float sdt[128], sca[128], sw[128];
    __shared__ float sAsum;
    if (tid < 128) sdt[tid] = (tid < q) ? dtb[((size_t)b*LSEQ + t0g + tid)*4 + hh] : 0.f;
    __syncthreads();
    if (tid == 0) {
        float Ah = -expf(A_log_l[hh]);
        float run = 0.f;
        for (int s = 0; s < 128; ++s) { run += sdt[s]*Ah; sca[s] = run; }
        sAsum = run;
        asum[(b*NHC + hh)*NCH + c] = run;
    }
    __syncthreads();
    if (tid < 128) sw[tid] = expf(sAsum - sca[tid]) * sdt[tid];
    __syncthreads();

    __shared__ float Xs[32][68];
    __shared__ float Bs[32][132];
    int n0 = (tid & 31) * 4, p0 = (tid >> 5) * 8;
    float acc[8][4] = {};
    const float* xrow = xBC + ((size_t)b*LSEQ + t0g) * 512;
    for (int st = 0; st < 4; ++st) {
        #pragma unroll
        for (int r = 0; r < 2; ++r) {
            int idx = tid + r*256;
            int s = idx >> 4, p4 = (idx & 15)*4;
            int sg = st*32 + s;
            float4 v = make_float4(0.f,0.f,0.f,0.f);
            if (sg < q) v = *(const float4*)(xrow + (size_t)sg*512 + hh*64 + p4);
            float wv = sw[sg];
            Xs[s][p4] = v.x*wv; Xs[s][p4+1] = v.y*wv; Xs[s][p4+2] = v.z*wv; Xs[s][p4+3] = v.w*wv;
        }
        #pragma unroll
        for (int r = 0; r < 4; ++r) {
            int idx = tid + r*256;
            int s = idx >> 5, n4 = (idx & 31)*4;
            int sg = st*32 + s;
            float4 v = make_float4(0.f,0.f,0.f,0.f);
            if (sg < q) v = *(const float4*)(xrow + (size_t)sg*512 + 256 + n4);
            *(float4*)&Bs[s][n4] = v;
        }
        __syncthreads();
        #pragma unroll 8
        for (int ss = 0; ss < 32; ++ss) {
            float4 x0 = *(const float4*)&Xs[ss][p0];
            float4 x1 = *(const float4*)&Xs[ss][p0+4];
            float xv[8] = {x0.x,x0.y,x0.z,x0.w,x1.x,x1.y,x1.z,x1.w};
            float4 bq = *(const float4*)&Bs[ss][n0];
            float bv[4] = {bq.x,bq.y,bq.z,bq.w};
            #pragma unroll
            for (int i = 0; i < 8; ++i)
                #pragma unroll
                for (int j = 0; j < 4; ++j)
                    acc[i][j] = fmaf(xv[i], bv[j], acc[i][j]);
        }
        __syncthreads();
    }
    size_t gbase = (((size_t)(b*NHC + hh))*NCH + c) * 8192;
    #pragma unroll
    for (int i = 0; i < 8; ++i) {
        float4 v; v.x = acc[i][0]; v.y = acc[i][1]; v.z = acc[i][2]; v.w = acc[i][3];
        *(float4*)(G + gbase + (size_t)(p0+i)*128 + n0) = v;
    }
}

// ---------------- SSD: chunk-level state recurrence ----------------
__global__ __launch_bounds__(256) void k_ssd_state(
    const float* __restrict__ G, const float* __restrict__ asum, float* __restrict__ Sinit)
{
    __shared__ float eA[NCH];
    int slice = blockIdx.x, bh = blockIdx.y;
    int tid = threadIdx.x;
    if (tid < NCH) eA[tid] = expf(asum[bh*NCH + tid]);
    __syncthreads();
    size_t base = (size_t)bh * NCH * 8192 + slice*1024 + tid*4;
    float s0=0.f, s1=0.f, s2=0.f, s3=0.f;
    for (int c = 0; c < NCH; ++c) {
        size_t off = base + (size_t)c*8192;
        float4 o; o.x=s0; o.y=s1; o.z=s2; o.w=s3;
        *(float4*)(Sinit + off) = o;
        float4 g = *(const float4*)(G + off);
        float da = eA[c];
        s0 = fmaf(s0, da, g.x); s1 = fmaf(s1, da, g.y);
        s2 = fmaf(s2, da, g.z); s3 = fmaf(s3, da, g.w);
    }
}

// ---------------- SSD: per-chunk output via bf16 MFMA ----------------
// Phase A: scores[t][s] = C·B^T (K=n), inter[t][p] = C·Sinit^T (K=n)
// Phase B: y[t][p] = (masked decayed scores)·X (K=s) + inter·exp(ca[t]) + D·x
// LDS union (shorts): phase A: Cs[128][72] | Bs[128][72] | Sis[64][72]   = 23040
//                     phase B: Sb[128][136] | Xt[64][136]               = 26112
__global__ __launch_bounds__(256) void k_ssd_out(
    const float* __restrict__ xBC, const float* __restrict__ dtb,
    const float* __restrict__ Sinit, const float* __restrict__ A_log_l,
    const float* __restrict__ D_l, float* __restrict__ y)
{
    __shared__ __align__(16) unsigned short smu[26112];
    __shared__ float sdt[128], sca[128];
    unsigned short* Cs  = smu;               // [128][72]
    unsigned short* Bsl = smu + 9216;        // [128][72]
    unsigned short* Sis = smu + 18432;       // [64][72]
    unsigned short* Sb  = smu;               // [128][136]
    unsigned short* Xt  = smu + 17408;       // [64][136]

    int c = blockIdx.x, hh = blockIdx.y, b = blockIdx.z;
    int t0g = c * 128;
    int q = LSEQ - t0g; if (q > 128) q = 128;
    int tid = threadIdx.x;
    int lane = tid & 63, wv = tid >> 6;
    int wm = (wv >> 1) * 64;        // t-offset of wave
    int ws0 = (wv & 1) * 64;        // s-offset (scores)
    int wp0 = (wv & 1) * 32;        // p-offset (inter / y)
    int fr = lane & 15;
    int fq = lane >> 4;

    if (tid < 128) sdt[tid] = (tid < q) ? dtb[((size_t)b*LSEQ + t0g + tid)*4 + hh] : 0.f;
    __syncthreads();
    if (tid == 0) {
        float Ah = -expf(A_log_l[hh]);
        float run = 0.f;
        for (int s = 0; s < 128; ++s) { run += sdt[s]*Ah; sca[s] = run; }
    }
    __syncthreads();

    const float* xrow = xBC + ((size_t)b*LSEQ + t0g) * 512;
    size_t sibase = (((size_t)(b*NHC + hh))*NCH + c) * 8192;

    f32x4 sacc[4][4] = {};
    f32x4 iacc[4][2] = {};

    // ---- phase A: two n-slices of 64 ----
    for (int ns = 0; ns < 128; ns += 64) {
        #pragma unroll
        for (int r = 0; r < 8; ++r) {
            int idx = (tid + r*256) * 4;          // over 128x64
            int row = idx >> 6, col = idx & 63;
            const float* gp = xrow + (size_t)row*512;
            float4 vc = *(const float4*)(gp + 384 + ns + col);
            float4 vb = *(const float4*)(gp + 256 + ns + col);
            *(ushort4*)&Cs[row*72 + col]  = f4bf(vc);
            *(ushort4*)&Bsl[row*72 + col] = f4bf(vb);
        }
        #pragma unroll
        for (int r = 0; r < 4; ++r) {
            int idx = (tid + r*256) * 4;          // over 64x64
            int row = idx >> 6, col = idx & 63;
            float4 v = *(const float4*)(Sinit + sibase + (size_t)row*128 + ns + col);
            *(ushort4*)&Sis[row*72 + col] = f4bf(v);
        }
        __syncthreads();
        #pragma unroll
        for (int kk = 0; kk < 2; ++kk) {
            int ko = kk*32 + fq*8;
            bf8_t af[4], bf_[4], sf[2];
            #pragma unroll
            for (int i = 0; i < 4; ++i)  af[i]  = *(const bf8_t*)&Cs[(wm + i*16 + fr)*72 + ko];
            #pragma unroll
            for (int j = 0; j < 4; ++j)  bf_[j] = *(const bf8_t*)&Bsl[(ws0 + j*16 + fr)*72 + ko];
            #pragma unroll
            for (int j = 0; j < 2; ++j)  sf[j]  = *(const bf8_t*)&Sis[(wp0 + j*16 + fr)*72 + ko];
            #pragma unroll
            for (int i = 0; i < 4; ++i) {
                #pragma unroll
                for (int j = 0; j < 4; ++j)
                    sacc[i][j] = __builtin_amdgcn_mfma_f32_16x16x32_bf16(af[i], bf_[j], sacc[i][j], 0, 0, 0);
                #pragma unroll
                for (int j = 0; j < 2; ++j)
                    iacc[i][j] = __builtin_amdgcn_mfma_f32_16x16x32_bf16(af[i], sf[j], iacc[i][j], 0, 0, 0);
            }
        }
        __syncthreads();
    }

    // ---- mask/decay scores -> Sb (bf16), stage Xt, init yacc ----
    float scat[4][4], ey[4][4];
    #pragma unroll
    for (int i = 0; i < 4; ++i)
        #pragma unroll
        for (int r = 0; r < 4; ++r) {
            scat[i][r] = sca[wm + i*16 + fq*4 + r];
            ey[i][r] = expf(scat[i][r]);
        }
    float scas[4], sdts[4];
    #pragma unroll
    for (int j = 0; j < 4; ++j) {
        int s = ws0 + j*16 + fr;
        scas[j] = sca[s]; sdts[j] = sdt[s];
    }
    #pragma unroll
    for (int i = 0; i < 4; ++i)
        #pragma unroll
        for (int j = 0; j < 4; ++j) {
            int s = ws0 + j*16 + fr;
            #pragma unroll
            for (int r = 0; r < 4; ++r) {
                int t = wm + i*16 + fq*4 + r;
                float val = 0.f;
                if (s <= t) val = sacc[i][j][r] * expf(scat[i][r] - scas[j]) * sdts[j];
                Sb[t*136 + s] = f2bf(val);
            }
        }
    #pragma unroll
    for (int r = 0; r < 8; ++r) {
        int idx = tid + r*256;                    // over [32 squads][64 p]
        int p = idx & 63, s0 = (idx >> 6) * 4;
        float4 v;
        v.x = xrow[(size_t)(s0+0)*512 + hh*64 + p];
        v.y = xrow[(size_t)(s0+1)*512 + hh*64 + p];
        v.z = xrow[(size_t)(s0+2)*512 + hh*64 + p];
        v.w = xrow[(size_t)(s0+3)*512 + hh*64 + p];
        *(ushort4*)&Xt[p*136 + s0] = f4bf(v);
    }
    f32x4 yacc[4][2];
    #pragma unroll
    for (int i = 0; i < 4; ++i)
        #pragma unroll
        for (int j = 0; j < 2; ++j)
            #pragma unroll
            for (int r = 0; r < 4; ++r)
                yacc[i][j][r] = iacc[i][j][r] * ey[i][r];
    __syncthreads();

    // ---- phase B: y += S~ @ X (K = s = 128) ----
    #pragma unroll
    for (int kk = 0; kk < 4; ++kk) {
        int ko = kk*32 + fq*8;
        bf8_t as_[4], xf[2];
        #pragma unroll
        for (int i = 0; i < 4; ++i) as_[i] = *(const bf8_t*)&Sb[(wm + i*16 + fr)*136 + ko];
        #pragma unroll
        for (int j = 0; j < 2; ++j) xf[j] = *(const bf8_t*)&Xt[(wp0 + j*16 + fr)*136 + ko];
        #pragma unroll
        for (int i = 0; i < 4; ++i)
            #pragma unroll
            for (int j = 0; j < 2; ++j)
                yacc[i][j] = __builtin_amdgcn_mfma_f32_16x16x32_bf16(as_[i], xf[j], yacc[i][j], 0, 0, 0);
    }

    // ---- epilogue: + D*x (f32 from global), store ----
    float Dh = D_l[hh];
    #pragma unroll
    for (int i = 0; i < 4; ++i)
        #pragma unroll
        for (int r = 0; r < 4; ++r) {
            int t = wm + i*16 + fq*4 + r;
            if (t < q) {
                #pragma unroll
                for (int j = 0; j < 2; ++j) {
                    int p = wp0 + j*16 + fr;
                    float xv = xrow[(size_t)t*512 + hh*64 + p];
                    y[((size_t)b*LSEQ + t0g + t)*256 + hh*64 + p] = yacc[i][j][r] + Dh*xv;
                }
            }
        }
}

// ---------------- gate (silu) + rmsnorm dim=256 (wave per row), bf16 out ----------------
__global__ __launch_bounds__(256) void k_gatenorm(
    const float* __restrict__ y, const float* __restrict__ proj,
    const float* __restrict__ gnw, unsigned short* __restrict__ out)
{
    int tid = threadIdx.x; int lane = tid & 63; int wv = tid >> 6;
    size_t row = (size_t)blockIdx.x*4 + wv;
    float4 yv = *(const float4*)(y + row*256 + lane*4);
    float4 gv = *(const float4*)(proj + row*772 + lane*4);
    float v0 = yv.x * siluf(gv.x);
    float v1 = yv.y * siluf(gv.y);
    float v2 = yv.z * siluf(gv.z);
    float v3 = yv.w * siluf(gv.w);
    float ss = v0*v0 + v1*v1 + v2*v2 + v3*v3;
    #pragma unroll
    for (int off = 32; off; off >>= 1) ss += __shfl_xor(ss, off);
    float sc = rsqrtf(ss*(1.f/256.f) + 1e-5f);
    float4 wv4 = *(const float4*)(gnw + lane*4);
    ushort4 o;
    o.x = f2bf(v0*sc*wv4.x); o.y = f2bf(v1*sc*wv4.y);
    o.z = f2bf(v2*sc*wv4.z); o.w = f2bf(v3*sc*wv4.w);
    *(ushort4*)(out + row*256 + lane*4) = o;
}

// ---------------- directional recombine ----------------
__global__ __launch_bounds__(256) void k_combine(
    const float* __restrict__ hn, float* __restrict__ xm, int total)
{
    int idx = blockIdx.x*256 + threadIdx.x;
    if (idx >= total) return;
    int d4 = idx & 31; int r = idx >> 5; int l = r % 1530; int b = r / 1530;
    int hg = l / 90, wg = l - hg*90; int l1 = wg*17 + hg;
    size_t base = (size_t)b * LSEQ;
    float4 a0 = *(const float4*)(hn + (base + l)*128 + d4*4);
    float4 a1 = *(const float4*)(hn + (base + LIMG + l1)*128 + d4*4);
    float4 a2 = *(const float4*)(hn + (base + 2*LIMG + (LIMG-1-l))*128 + d4*4);
    float4 a3 = *(const float4*)(hn + (base + 3*LIMG + (LIMG-1-l1))*128 + d4*4);
    float4 o; o.x = a0.x+a1.x+a2.x+a3.x; o.y = a0.y+a1.y+a2.y+a3.y;
    o.z = a0.z+a1.z+a2.z+a3.z; o.w = a0.w+a1.w+a2.w+a3.w;
    *(float4*)(xm + ((size_t)b*LIMG + l)*128 + d4*4) = o;
}

// ---------------- un-patchify scatter ----------------
__global__ __launch_bounds__(256) void k_unpatch(
    const float* __restrict__ rbuf, float* __restrict__ out, int total)
{
    int idx = blockIdx.x*256 + threadIdx.x;
    if (idx >= total) return;
    int addr = idx*4;
    int col = addr % 720; int t = addr / 720; int row = t % 340; t /= 340;
    int cc = t % 3; int b = t / 3;
    int hg = row/20, ii = row - hg*20, wg = col >> 3, j0 = col & 7;
    size_t rb = ((size_t)(b*LIMG) + hg*90 + wg)*480 + ii*24 + cc;
    float4 v;
    v.x = rbuf[rb + (j0+0)*3];
    v.y = rbuf[rb + (j0+1)*3];
    v.z = rbuf[rb + (j0+2)*3];
    v.w = rbuf[rb + (j0+3)*3];
    *(float4*)(out + addr) = v;
}

extern "C" void kernel_launch(void* const* d_in, const int* in_sizes, int n_in,
                              void* d_out, int out_size, void* d_ws, size_t ws_size,
                              hipStream_t stream) {
    (void)in_sizes; (void)n_in;
    const float* x      = (const float*)d_in[0];
    const float* W_pe   = (const float*)d_in[1];
    const float* b_pe   = (const float*)d_in[2];
    const float* norm_w = (const float*)d_in[3];
    const float* in_w   = (const float*)d_in[4];
    const float* in_b   = (const float*)d_in[5];
    const float* conv_w = (const float*)d_in[6];
    const float* conv_b = (const float*)d_in[7];
    const float* dt_bias= (const float*)d_in[8];
    const float* A_log  = (const float*)d_in[9];
    const float* Dp     = (const float*)d_in[10];
    const float* gn_w   = (const float*)d_in[11];
    const float* out_w  = (const float*)d_in[12];
    const float* out_b  = (const float*)d_in[13];
    const float* normf_w= (const float*)d_in[14];
    const float* r1_w   = (const float*)d_in[15];
    const float* r1_b   = (const float*)d_in[16];
    const float* r2_w   = (const float*)d_in[17];
    const float* r2_b   = (const float*)d_in[18];

    auto needed = [](int Bc) -> size_t {
        size_t o = 0;
        auto al = [&](size_t n){ o += (n + 63) & ~(size_t)63; };
        al((size_t)Bc*LSEQ*128);       // h
        al((size_t)Bc*LSEQ*128);       // hn
        al((size_t)Bc*LSEQ*772);       // proj
        al((size_t)Bc*LSEQ*512);       // xbc
        al((size_t)Bc*LSEQ*4);         // dtb
        al((size_t)Bc*NHC*NCH*8192);   // G
        al((size_t)Bc*NHC*NCH*8192);   // Sinit
        al((size_t)Bc*NHC*NCH);        // asum
        al(229376); al(65536); al(16384); al(61440); al(61440);
        return o * 4;
    };
    int Bc = 0;
    const int cands[4] = {8, 4, 2, 1};
    for (int i = 0; i < 4; ++i) if (needed(cands[i]) <= ws_size) { Bc = cands[i]; break; }
    if (Bc == 0) {
        float mv = (float)((double)ws_size / (1024.0*1024.0));
        k_marker<<<(out_size+255)/256, 256, 0, stream>>>((float*)d_out, out_size, mv);
        return;
    }

    float* ws = (float*)d_ws;
    size_t o = 0;
    auto alloc = [&](size_t n){ size_t r = o; o += (n + 63) & ~(size_t)63; return r; };
    float* h     = ws + alloc((size_t)Bc*LSEQ*128);
    float* hn    = ws + alloc((size_t)Bc*LSEQ*128);
    float* proj  = ws + alloc((size_t)Bc*LSEQ*772);
    float* xbc   = ws + alloc((size_t)Bc*LSEQ*512);
    float* dtb   = ws + alloc((size_t)Bc*LSEQ*4);
    float* G     = ws + alloc((size_t)Bc*NHC*NCH*8192);
    float* Sini  = ws + alloc((size_t)Bc*NHC*NCH*8192);
    float* asum  = ws + alloc((size_t)Bc*NHC*NCH);
    unsigned short* inwB  = (unsigned short*)(ws + alloc(229376));
    unsigned short* outwB = (unsigned short*)(ws + alloc(65536));
    float* r1T   = ws + alloc(16384);
    float* r2T   = ws + alloc(61440);
    float* peT   = ws + alloc(61440);
    float* ybuf  = G;
    unsigned short* hnb  = (unsigned short*)hn;
    unsigned short* ynb  = (unsigned short*)xbc;
    float* xm    = proj;
    float* t1    = proj + (size_t)Bc*LIMG*128;
    float* rbuf  = t1 + (size_t)Bc*LIMG*128;

    k_wtrans<<<1792, 256, 0, stream>>>(W_pe, in_w, out_w, r1_w, r2_w, peT, inwB, outwB, r1T, r2T);

    for (int bc = 0; bc < 8; bc += Bc) {
        const float* xc = x + (size_t)bc*3*340*720;
        float* outc = (float*)d_out + (size_t)bc*3*340*720;
        int rowsL = Bc*LSEQ;
        int rowsI = Bc*LIMG;
        int npatch = Bc*LIMG;
        int mb128 = (rowsL + 127) / 128;
        int mbI = (rowsI + 63) / 64;

        k_embed2<<<(npatch + 31)/32, 256, 0, stream>>>(xc, peT, b_pe, h, npatch);
        for (int l = 0; l < 4; ++l) {
            k_rms128<1><<<(rowsL + 3)/4, 256, 0, stream>>>(h, norm_w + l*128, hnb, rowsL);
            k_bgemm<0><<<dim3(mb128, 7), 256, 0, stream>>>(hnb, inwB + (size_t)l*114688,
                                                           in_b + l*772, proj, 772,
                                                           rowsL, 772, 128);
            k_conv<<<dim3(383, Bc), 256, 0, stream>>>(proj, conv_w + l*2048, conv_b + l*512,
                                                      dt_bias + l*4, xbc, dtb);
            k_ssd_pre<<<dim3(NCH, NHC, Bc), 256, 0, stream>>>(xbc, dtb, A_log + l*4, G, asum);
            k_ssd_state<<<dim3(8, Bc*NHC), 256, 0, stream>>>(G, asum, Sini);
            k_ssd_out<<<dim3(NCH, NHC, Bc), 256, 0, stream>>>(xbc, dtb, Sini, A_log + l*4,
                                                              Dp + l*4, ybuf);
            k_gatenorm<<<rowsL/4, 256, 0, stream>>>(ybuf, proj, gn_w + l*256, ynb);
            k_bgemm<2><<<dim3(mb128, 1), 256, 0, stream>>>(ynb, outwB + (size_t)l*32768,
                                                           out_b + l*128, h, 128,
                                                           rowsL, 128, 256);
        }
        k_rms128<0><<<(rowsL + 3)/4, 256, 0, stream>>>(h, normf_w, hn, rowsL);
        k_combine<<<(rowsI*32 + 255)/256, 256, 0, stream>>>(hn, xm, rowsI*32);
        k_gemm<1><<<dim3(mbI, 2), 256, 0, stream>>>(xm, 128, r1T, 128, r1_b, t1, 128, rowsI, 128, 128);
        k_gemm<0><<<dim3(mbI, 8), 256, 0, stream>>>(t1, 128, r2T, 480, r2_b, rbuf, 480, rowsI, 480, 128);
        k_unpatch<<<(Bc*183600 + 255)/256, 256, 0, stream>>>(rbuf, outc, Bc*183600);
    }
}